// Round 10
// baseline (3251.927 us; speedup 1.0000x reference)
//
#include <hip/hip_runtime.h>
#include <hip/hip_bf16.h>

#define Bsz   1024
#define Lseq  50
#define Din   4
#define Hd    512
#define Tlen  30
#define NWG   256

typedef __hip_bfloat16 bf16;
typedef short s16x8 __attribute__((ext_vector_type(8)));
typedef short s16x4 __attribute__((ext_vector_type(4)));
typedef float f32x4 __attribute__((ext_vector_type(4)));
typedef int   i32x2 __attribute__((ext_vector_type(2)));

__device__ __forceinline__ float bf2f(bf16 x){ return __bfloat162float(x); }
__device__ __forceinline__ bf16  f2bf(float x){ return __float2bfloat16(x); }
__device__ __forceinline__ float bfbits2f(short u){
    union { unsigned int ui; float f; } v;
    v.ui = ((unsigned int)(unsigned short)u) << 16;
    return v.f;
}
__device__ __forceinline__ short f2bfbits(float x){
    bf16 h = f2bf(x); short s; __builtin_memcpy(&s, &h, 2); return s;
}
__device__ __forceinline__ float sigm(float x){ return 1.0f/(1.0f + __expf(-x)); }
__device__ __forceinline__ float ftanh(float x){
    const float e = __expf(2.0f*x);
    return 1.0f - 2.0f/(e + 1.0f);
}
__device__ __forceinline__ i32x2 pack4(float a, float b, float c, float d){
    i32x2 v;
    v[0] = (int)(unsigned short)f2bfbits(a) | ((int)(unsigned short)f2bfbits(b) << 16);
    v[1] = (int)(unsigned short)f2bfbits(c) | ((int)(unsigned short)f2bfbits(d) << 16);
    return v;
}
__device__ __forceinline__ int pack2(float a, float b){
    return (int)(unsigned short)f2bfbits(a) | ((int)(unsigned short)f2bfbits(b) << 16);
}
// L3-bypass 8B load (sc0 sc1): reads the device coherence point.
__device__ __forceinline__ s16x4 sc_load_b64(const void* p){
    i32x2 v;
    asm volatile("global_load_dwordx2 %0, %1, off sc0 sc1\n\ts_waitcnt vmcnt(0)"
                 : "=v"(v) : "v"(p) : "memory");
    s16x4 r; __builtin_memcpy(&r, &v, 8); return r;
}
// L3-direct 4B store (sc0 sc1).  Drained by __syncthreads' vmcnt(0); the
// rank0 __threadfence in global rounds additionally orders it.
__device__ __forceinline__ void sc_store_b32(void* p, int v){
    asm volatile("global_store_dword %0, %1, off sc0 sc1" :: "v"(p), "v"(v) : "memory");
}

// ---------------- ws layout (bytes) ----------------
#define OFF_ABUF0   (0u)
#define OFF_ABUF1   (2u<<20)
#define OFF_HT0     (4u<<20)
#define OFF_HT1     (5u<<20)
#define OFF_ATTNAP  (8u<<20)
#define OFF_XDEC    (9u<<20)
#define OFF_FLAG    ((9u<<20) + (16u<<10))
#define OFF_COMBWR  ((9u<<20) + (32u<<10))
#define OFF_ATTNWR  ((9u<<20) + (600u<<10))
#define OFF_FLAGS   ((9u<<20) + (704u<<10))
#define OFF_WCACHE  (10u<<20)
#define OFF_ENCOUT  (18u<<20)

// wcache element offsets (bf16 elements), 8-elem aligned per array
#define WC_INPUT 0
#define WC_EWIH  204800
#define WC_EWHH  212992
#define WC_EBIH  1261568
#define WC_EBHH  1263616
#define WC_AW    1265664
#define WC_AB    1291464
#define WC_CW    1291520
#define WC_CB    1555712
#define WC_DWIH  1556224
#define WC_DWHH  2604800
#define WC_DBIH  3653376
#define WC_DBHH  3655424
#define WC_OW    3657472
#define WC_OB    3659520
#define WC_TOTAL 3659524

__device__ __constant__ int WOFF[15] = {
    WC_INPUT, WC_EWIH, WC_EWHH, WC_EBIH, WC_EBHH, WC_AW, WC_AB, WC_CW,
    WC_CB, WC_DWIH, WC_DWHH, WC_DBIH, WC_DBHH, WC_OW, WC_OB };
__device__ __constant__ int WNUM[15] = {
    204800, 8192, 1048576, 2048, 2048, 25800, 50, 264192,
    512, 1048576, 1048576, 2048, 2048, 2048, 4 };

struct Ptrs15 { const void* p[15]; };

__global__ void probe_kernel(const unsigned int* __restrict__ w, int* flag){
    __shared__ int cnt;
    if (threadIdx.x == 0) cnt = 0;
    __syncthreads();
    int c = 0;
    for (int i = threadIdx.x; i < 4096; i += 256){
        unsigned e = (w[i] >> 7) & 0xFFu;
        c += (e >= 0x80u) ? 1 : 0;
    }
    atomicAdd(&cnt, c);
    __syncthreads();
    if (threadIdx.x == 0) *flag = (cnt > 400) ? 1 : 0;
}

__global__ __launch_bounds__(256) void convert_kernel(
    Ptrs15 srcs, const int* __restrict__ flag, bf16* __restrict__ dst)
{
    const int f = *flag;
    for (int idx = blockIdx.x*256 + threadIdx.x; idx < WC_TOTAL;
         idx += gridDim.x*256){
        int a = 0;
#pragma unroll
        for (int j = 1; j < 15; ++j) if (idx >= WOFF[j]) a = j;
        const int local = idx - WOFF[a];
        if (local >= WNUM[a]) continue;
        bf16 v;
        if (f) v = f2bf(((const float*)srcs.p[a])[local]);
        else   v = ((const bf16*)srcs.p[a])[local];
        dst[idx] = v;
    }
}

__global__ __launch_bounds__(256) void setup_kernel(
    bf16* __restrict__ Abuf0, bf16* __restrict__ Abuf1,
    bf16* __restrict__ combWr, bf16* __restrict__ attnWr,
    const bf16* __restrict__ cWc, const bf16* __restrict__ aWc)
{
    const unsigned idx = blockIdx.x*256u + threadIdx.x;
    if (idx < (unsigned)Bsz*Hd){
        const unsigned row = idx >> 9, col = idx & (Hd-1);
        const bf16 z = f2bf(0.0f);
        Abuf0[(size_t)row*1024 + Hd + col] = z;
        Abuf1[(size_t)row*1024 + Hd + col] = z;
    }
    if (idx < (unsigned)Hd*Hd)
        combWr[idx] = cWc[(size_t)(idx >> 9)*(Hd+Din) + Din + (idx & (Hd-1))];
    if (idx < (unsigned)Lseq*Hd)
        attnWr[idx] = aWc[(size_t)(idx >> 9)*(Hd+Din) + Din + (idx & (Hd-1))];
}

struct MegaP {
    const bf16 *input, *eWih, *eWhh, *ebih, *ebhh;
    const bf16 *aW, *ab, *cW, *cb, *dWih, *dWhh, *dbih, *dbhh, *oW, *ob;
    const bf16 *combWr, *attnWr;
    bf16 *A0, *A1, *encout, *attnap, *xdec;
    bf16 *hT0, *hT1;
    int *xcnt, *gcnt, *grel, *xccmap;
    const int *flag;
    void *dout;
};

#define WSTRIDE 536   // LDS weight row stride in shorts (16B aligned, low-conflict)

// ---------------------------------------------------------------------------
// Persistent megakernel v13 = v12/v8 (confirmed best: 3154us, reproduced
// across two containers) + register-hoisting of step-invariant decoder data.
// Zero sync edits.  Rationale: every decoder round ends with buffer_inv (L1
// wipe), so step-invariant data (comb weights, oW, attention x-weights) is
// re-fetched from L2 every round on the critical path.  Hoist to VGPRs once:
//   - cwreg[16] (s16x8): D2's combWr fragments (64 VGPRs)
//   - owreg[4]  (s16x8): pred's oW rows at this lane's stride positions
//   - awx/abv: attention x-part weights for this lane
// VGPR ~128 -> ~210, under the 256 cap at launch_bounds(512,2); occupancy is
// LDS-bound (1 WG/CU) and unchanged.  Verification signal: VGPR_Count jump.
// Ledger: poll transport ~0 (v7) · fence storm -180us (v8) · gather ~0 (v6)
// · critical-wave overload -530us (v9) · attnWrT -650us (v11, A/A-confirmed
// harmful) · split-barrier n/a (v10, infra).
// ---------------------------------------------------------------------------
__global__ __launch_bounds__(512, 2) void mega_kernel(MegaP P)
{
    __shared__ short w1_lds[64*WSTRIDE];   // 68,608 B (dec W_ih slice)
    __shared__ short w2_lds[64*WSTRIDE];   // 68,608 B (enc W_hh, then dec W_hh)
    __shared__ short hr_s[4][Hd];          // 4 KB
    __shared__ float ctx_s[2][4][8][64];   // 16 KB
    __shared__ float aw_s[4][64];          // 1 KB
    __shared__ int   xmap_s[NWG];          // 1 KB
    __shared__ int   info_s[2];

    const int wg = blockIdx.x, tid = threadIdx.x;
    const int wave = tid >> 6, lane = tid & 63;
    const int quad = lane >> 4, l15 = lane & 15;
    const int lbase = lane & ~3;
    const int f32out = *P.flag;

    const int grp = wg & 7, rank = wg >> 3;

    int ep = 0, gep = 0;

    // local arrive+wait: one fetch_add + one poller per WG
    auto bar_local = [&](){
        ++ep;
        __syncthreads();                      // drains vmcnt (incl. sc stores)
        if (tid == 0){
            int* c = P.xcnt + grp*32;
            __hip_atomic_fetch_add(c, 1, __ATOMIC_RELAXED, __HIP_MEMORY_SCOPE_SYSTEM);
            while (__hip_atomic_load(c, __ATOMIC_RELAXED, __HIP_MEMORY_SCOPE_SYSTEM) < 32*ep)
                __builtin_amdgcn_s_sleep(2);
        }
        __syncthreads();
    };
    // global arrive+wait.  fmode: 1 = rank0-per-grp fence (grp==XCD verified),
    // 2 = all-WG fence (fallback).
    auto bar_global = [&](int fmode){
        ++ep; ++gep;
        __syncthreads();
        if (tid == 0){
            if (fmode == 2) __threadfence();
            int* c = P.xcnt + grp*32;
            __hip_atomic_fetch_add(c, 1, __ATOMIC_RELAXED, __HIP_MEMORY_SCOPE_SYSTEM);
            if (rank == 0){
                while (__hip_atomic_load(c, __ATOMIC_RELAXED, __HIP_MEMORY_SCOPE_SYSTEM) < 32*ep)
                    __builtin_amdgcn_s_sleep(2);
                if (fmode == 1) __threadfence();   // one L2 writeback per XCD
                __hip_atomic_fetch_add(P.gcnt, 1, __ATOMIC_RELAXED, __HIP_MEMORY_SCOPE_SYSTEM);
                while (__hip_atomic_load(P.gcnt, __ATOMIC_RELAXED, __HIP_MEMORY_SCOPE_SYSTEM) < 8*gep)
                    __builtin_amdgcn_s_sleep(2);
                __hip_atomic_store(P.grel + grp*32, gep, __ATOMIC_RELAXED, __HIP_MEMORY_SCOPE_SYSTEM);
            } else {
                int* r = P.grel + grp*32;
                while (__hip_atomic_load(r, __ATOMIC_RELAXED, __HIP_MEMORY_SCOPE_SYSTEM) < gep)
                    __builtin_amdgcn_s_sleep(2);
            }
        }
        __syncthreads();
    };

    // full fallback: global + L2 invalidate (safe under any WG placement)
    auto GSYNCF = [&](){
        bar_global(2);
        asm volatile("buffer_inv sc0 sc1" ::: "memory");
        __syncthreads();
    };

    // ---- XCD mapping verification ----
    if (tid == 0){
        int xcc = 0;
        asm volatile("s_getreg_b32 %0, hwreg(HW_REG_XCC_ID)" : "=s"(xcc));
        P.xccmap[wg] = xcc & 7;
    }
    GSYNCF();
    if (tid < NWG) xmap_s[tid] = P.xccmap[tid];
    __syncthreads();
    if (tid == 0){
        int ok = 1;
        for (int g = 0; g < 8; ++g){
            const int x0 = xmap_s[g];
            for (int i = 1; i < 32; ++i) ok &= (xmap_s[i*8 + g] == x0);
        }
        info_s[0] = ok;
    }
    __syncthreads();
    const int bal = info_s[0];

    // global sync: rank0-per-XCD fence + counter round + L1-only inv
    auto GSYNCL = [&](){
        if (!bal){ GSYNCF(); return; }
        bar_global(1);
        asm volatile("buffer_inv" ::: "memory");
        __syncthreads();
    };
    // XCD-local sync, L1-only inv
    auto XSYNC = [&](){
        if (!bal){ GSYNCF(); return; }
        bar_local();
        asm volatile("buffer_inv" ::: "memory");
    };

    bf16* bufs[2] = { P.A0, P.A1 };

    // ---- gates tiling: 128 rows x 64 gate-cols per WG ----
    const int bm0 = grp*128, hc0 = rank*16;
    const int wm = wave >> 1, wn = wave & 1;      // 4 x 2 waves (32x32 each)
    const int arow0 = bm0 + wm*32 + l15;

    int ng[2];
#pragma unroll
    for (int nf = 0; nf < 2; ++nf){
        const int n = wn*32 + nf*16 + l15;        // 0..63
        ng[nf] = (n & 3)*Hd + hc0 + (n >> 2);
    }

    // ================= ENCODER =================
    float bias_e[2], wxv_e[2][4];
#pragma unroll
    for (int nf = 0; nf < 2; ++nf){
        bias_e[nf] = bf2f(P.ebih[ng[nf]]) + bf2f(P.ebhh[ng[nf]]);
        const s16x4 t4 = *reinterpret_cast<const s16x4*>(P.eWih + (size_t)ng[nf]*Din);
#pragma unroll
        for (int d = 0; d < 4; ++d) wxv_e[nf][d] = bfbits2f(t4[d]);
    }

    // enc W_hh slice -> w2_lds  (64 local cols x 512 K)
    for (int i = tid; i < 64*64; i += 512){
        const int col = i >> 6, k8 = (i & 63)*8;
        const int g = (col & 3)*Hd + hc0 + (col >> 2);
        const s16x8 v = *reinterpret_cast<const s16x8*>(P.eWhh + (size_t)g*Hd + k8);
        *reinterpret_cast<s16x8*>(&w2_lds[col*WSTRIDE + k8]) = v;
    }
    __syncthreads();

    float creg[2][2][4];
#pragma unroll
    for (int a = 0; a < 2; ++a)
#pragma unroll
        for (int b = 0; b < 2; ++b)
#pragma unroll
            for (int r = 0; r < 4; ++r) creg[a][b][r] = 0.0f;

    for (int t = 0; t < Lseq; ++t){
        const bf16* Ain = bufs[t&1] + Hd;
        bf16* hout = bufs[(t+1)&1] + Hd;

        f32x4 acc[2][2];
#pragma unroll
        for (int mf=0; mf<2; ++mf)
#pragma unroll
            for (int nf=0; nf<2; ++nf) acc[mf][nf] = (f32x4)0.0f;

        s16x8 afr[2], bfr[2];
#pragma unroll
        for (int sl = 0; sl < 16; ++sl){
#pragma unroll
            for (int mf = 0; mf < 2; ++mf)
                afr[mf] = *reinterpret_cast<const s16x8*>(
                    Ain + (size_t)(arow0 + mf*16)*1024 + sl*32 + quad*8);
#pragma unroll
            for (int nf = 0; nf < 2; ++nf){
                const int nl = wn*32 + nf*16 + l15;
                bfr[nf] = *reinterpret_cast<const s16x8*>(
                    &w2_lds[nl*WSTRIDE + sl*32 + quad*8]);
            }
#pragma unroll
            for (int mf = 0; mf < 2; ++mf)
#pragma unroll
                for (int nf = 0; nf < 2; ++nf)
                    acc[mf][nf] = __builtin_amdgcn_mfma_f32_16x16x32_bf16(
                        afr[mf], bfr[nf], acc[mf][nf], 0, 0, 0);
        }

#pragma unroll
        for (int mf = 0; mf < 2; ++mf){
            const int mb = bm0 + wm*32 + mf*16 + quad*4;
            s16x4 xts[4];
#pragma unroll
            for (int r = 0; r < 4; ++r)
                xts[r] = *reinterpret_cast<const s16x4*>(
                    P.input + ((size_t)(mb+r)*Lseq + t)*Din);
#pragma unroll
            for (int nf = 0; nf < 2; ++nf){
                const int n_loc = wn*32 + nf*16 + l15;
                float hvv[4];
#pragma unroll
                for (int r = 0; r < 4; ++r){
                    float gv = acc[mf][nf][r] + bias_e[nf]
                             + bfbits2f(xts[r][0])*wxv_e[nf][0]
                             + bfbits2f(xts[r][1])*wxv_e[nf][1]
                             + bfbits2f(xts[r][2])*wxv_e[nf][2]
                             + bfbits2f(xts[r][3])*wxv_e[nf][3];
                    const float gi = __shfl(gv, lbase+0);
                    const float gf = __shfl(gv, lbase+1);
                    const float gg = __shfl(gv, lbase+2);
                    const float go = __shfl(gv, lbase+3);
                    const float cn = sigm(gf)*creg[mf][nf][r] + sigm(gi)*ftanh(gg);
                    creg[mf][nf][r] = cn;
                    hvv[r] = sigm(go)*ftanh(cn);
                }
                if ((lane & 3) == 0){
                    const int hcol = hc0 + (n_loc >> 2);
#pragma unroll
                    for (int r = 0; r < 4; ++r){
                        const bf16 hb = f2bf(hvv[r]);
                        hout[(size_t)(mb+r)*1024 + hcol] = hb;
                        P.encout[((size_t)(mb+r)*Lseq + t)*Hd + hcol] = hb;
                    }
                    if (t == Lseq-1){
                        // stage h transposed for decoder t=0 (reads hT1)
                        sc_store_b32(P.hT1 + ((hcol*2+0)<<9) + (mb>>1), pack2(hvv[0], hvv[2]));
                        sc_store_b32(P.hT1 + ((hcol*2+1)<<9) + (mb>>1), pack2(hvv[1], hvv[3]));
                    }
                }
            }
        }
        if (t == Lseq-1) GSYNCL(); else XSYNC();
    }

    // ================= DECODER setup =================
    // dec weights -> LDS
    for (int i = tid; i < 64*64; i += 512){
        const int col = i >> 6, k8 = (i & 63)*8;
        const int g = (col & 3)*Hd + hc0 + (col >> 2);
        *reinterpret_cast<s16x8*>(&w1_lds[col*WSTRIDE + k8]) =
            *reinterpret_cast<const s16x8*>(P.dWih + (size_t)g*Hd + k8);
        *reinterpret_cast<s16x8*>(&w2_lds[col*WSTRIDE + k8]) =
            *reinterpret_cast<const s16x8*>(P.dWhh + (size_t)g*Hd + k8);
    }

    float bias_d[2];
#pragma unroll
    for (int nf = 0; nf < 2; ++nf)
        bias_d[nf] = bf2f(P.dbih[ng[nf]]) + bf2f(P.dbhh[ng[nf]]);

    const int b0 = grp*128 + rank*4;
    const int s_uni = b0 >> 9;
    const int p0 = b0 & (Hd-1);

    // enc_out slice -> registers: wave (rr, half) holds row b0+rr, l = half*25+i
    const int rr = wave & 3, half = wave >> 2;
    s16x8 ereg[25];
    {
        const bf16* eb = P.encout + (size_t)(b0 + rr)*Lseq*Hd + lane*8;
#pragma unroll
        for (int i = 0; i < 25; ++i)
            ereg[i] = *reinterpret_cast<const s16x8*>(eb + (size_t)(half*25 + i)*Hd);
    }

    // comb tile: wave covers rows bm0+wave*16, cols ccol
    const int ccol = hc0 + l15;   // 16 comb cols per WG (rank*16..+16)
    float bias_c, wxv_c[4];
    {
        bias_c = bf2f(P.cb[ccol]);
        const s16x4 t4 = *reinterpret_cast<const s16x4*>(P.cW + (size_t)ccol*(Hd+Din));
#pragma unroll
        for (int d = 0; d < 4; ++d) wxv_c[d] = bfbits2f(t4[d]);
    }

    // ---- step-invariant data -> registers (survives the per-round L1 inv) ----
    // D2 comb weight fragments: 16 x s16x8 = 64 VGPRs
    s16x8 cwreg[16];
#pragma unroll
    for (int kk = 0; kk < 16; ++kk)
        cwreg[kk] = *reinterpret_cast<const s16x8*>(
            P.combWr + (size_t)ccol*Hd + kk*32 + quad*8);
    // pred oW rows at this lane's stride-64 positions: 4 x s16x8 = 16 VGPRs
    s16x8 owreg[4];
#pragma unroll
    for (int r2 = 0; r2 < 4; ++r2){
#pragma unroll
        for (int j = 0; j < 8; ++j){
            short s; __builtin_memcpy(&s, P.oW + r2*Hd + lane + j*64, 2);
            owreg[r2][j] = s;
        }
    }
    // attention x-part weights + bias for this lane (guarded: aW has Lseq rows)
    float abv = 0.0f, awx[4] = {0.f,0.f,0.f,0.f};
    if (lane < Lseq){
        abv = bf2f(P.ab[lane]);
        const s16x4 t4 = *reinterpret_cast<const s16x4*>(P.aW + (size_t)lane*(Hd+Din));
#pragma unroll
        for (int d = 0; d < 4; ++d) awx[d] = bfbits2f(t4[d]);
    }
    const float ob0 = bf2f(P.ob[0]), ob1 = bf2f(P.ob[1]);
    const float ob2 = bf2f(P.ob[2]), ob3 = bf2f(P.ob[3]);
    __syncthreads();  // LDS fills complete

    for (int t = 0; t < Tlen; ++t){
        const int p = t & 1;
        const bf16* hprev = bufs[p] + Hd;

        // ---- D1: hr staging (coalesced from transposed hT) + pred(t-1) + attention ----
        {
            const bf16* hTr = (t & 1) ? P.hT0 : P.hT1;   // written prev step / by encoder
            const int q = tid >> 7;                      // 0..3 -> hr row
            const int i0 = (tid & 127) << 2;             // 0..508 step 4
            const s16x4 hv = sc_load_b64(hTr + (size_t)(((p0 + q)*2 + s_uni)<<9) + i0);
            *reinterpret_cast<s16x4*>(&hr_s[q][i0]) = hv;
        }
        __syncthreads();

        if (wave < 4){
            const int b = b0 + wave;
            float x0, x1, x2, x3;
            if (t == 0){
                const bf16* xp = P.input + ((size_t)b*Lseq + (Lseq-1))*Din;
                x0 = bf2f(xp[0]); x1 = bf2f(xp[1]); x2 = bf2f(xp[2]); x3 = bf2f(xp[3]);
            } else {
                float q0=0.f, q1=0.f, q2=0.f, q3=0.f;
                const bf16* hb = hprev + (size_t)b*1024;
#pragma unroll
                for (int j = 0; j < 8; ++j){
                    const float hv = bf2f(hb[lane + j*64]);
                    q0 += hv*bfbits2f(owreg[0][j]);
                    q1 += hv*bfbits2f(owreg[1][j]);
                    q2 += hv*bfbits2f(owreg[2][j]);
                    q3 += hv*bfbits2f(owreg[3][j]);
                }
#pragma unroll
                for (int off = 32; off; off >>= 1){
                    q0 += __shfl_down(q0, off); q1 += __shfl_down(q1, off);
                    q2 += __shfl_down(q2, off); q3 += __shfl_down(q3, off);
                }
                x0 = __shfl(q0,0) + ob0;
                x1 = __shfl(q1,0) + ob1;
                x2 = __shfl(q2,0) + ob2;
                x3 = __shfl(q3,0) + ob3;
                if (lane == 0){
                    const size_t o = ((size_t)b*Tlen + (t-1))*Din;
                    if (f32out){
                        float* dp = (float*)P.dout + o;
                        dp[0]=x0; dp[1]=x1; dp[2]=x2; dp[3]=x3;
                    } else {
                        *reinterpret_cast<i32x2*>((bf16*)P.dout + o) = pack4(x0,x1,x2,x3);
                    }
                }
            }
            if (lane == 0)
                *reinterpret_cast<i32x2*>(P.xdec + (size_t)b*Din) = pack4(x0,x1,x2,x3);

            float logit = -3.0e38f;
            if (lane < Lseq){
                float a0 = abv + x0*awx[0] + x1*awx[1] + x2*awx[2] + x3*awx[3];
                float a1 = 0.f, a2 = 0.f, a3 = 0.f;
                const bf16* wr = P.attnWr + (size_t)lane*Hd;
                for (int j = 0; j < Hd; j += 16){
                    float t4[4] = {0.f,0.f,0.f,0.f};
#pragma unroll
                    for (int q = 0; q < 4; ++q){
                        const s16x4 hw = *reinterpret_cast<const s16x4*>(&hr_s[wave][j + q*4]);
                        const s16x4 wv = *reinterpret_cast<const s16x4*>(wr + j + q*4);
                        t4[q] = bfbits2f(hw[0])*bfbits2f(wv[0]) + bfbits2f(hw[1])*bfbits2f(wv[1])
                              + bfbits2f(hw[2])*bfbits2f(wv[2]) + bfbits2f(hw[3])*bfbits2f(wv[3]);
                    }
                    a0 += t4[0]; a1 += t4[1]; a2 += t4[2]; a3 += t4[3];
                }
                logit = (a0 + a1) + (a2 + a3);
            }
            float mx = logit;
#pragma unroll
            for (int off = 32; off; off >>= 1) mx = fmaxf(mx, __shfl_xor(mx, off));
            const float e = (lane < Lseq) ? __expf(logit - mx) : 0.0f;
            float se = e;
#pragma unroll
            for (int off = 32; off; off >>= 1) se += __shfl_xor(se, off);
            aw_s[wave][lane] = e / se;
        }
        __syncthreads();

        // context entirely from registers
        {
            float acc8[8] = {0.f,0.f,0.f,0.f,0.f,0.f,0.f,0.f};
#pragma unroll
            for (int i = 0; i < 25; ++i){
                const float w = aw_s[rr][half*25 + i];
#pragma unroll
                for (int q = 0; q < 8; ++q) acc8[q] += w * bfbits2f(ereg[i][q]);
            }
#pragma unroll
            for (int q = 0; q < 8; ++q) ctx_s[half][rr][q][lane] = acc8[q];
        }
        __syncthreads();

        if (wave < 4){
            const int b = b0 + wave;
            s16x8 ov;
#pragma unroll
            for (int q = 0; q < 8; ++q)
                ov[q] = f2bfbits(ctx_s[0][wave][q][lane] + ctx_s[1][wave][q][lane]);
            *reinterpret_cast<s16x8*>(P.attnap + (size_t)b*Hd + lane*8) = ov;
        }
        XSYNC();

        // ---- D2: comb GEMM (128 rows x 16 cols per WG), weights in VGPRs ----
        {
            f32x4 cacc = (f32x4)0.0f;
            const bf16* Ab = P.attnap + (size_t)(bm0 + wave*16 + l15)*Hd + quad*8;
#pragma unroll
            for (int kk = 0; kk < 16; ++kk){
                const s16x8 afr2 = *reinterpret_cast<const s16x8*>(Ab + kk*32);
                cacc = __builtin_amdgcn_mfma_f32_16x16x32_bf16(afr2, cwreg[kk], cacc, 0, 0, 0);
            }
            bf16* outp = bufs[p];
#pragma unroll
            for (int r = 0; r < 4; ++r){
                const int m = bm0 + wave*16 + quad*4 + r;
                const s16x4 xt = *reinterpret_cast<const s16x4*>(P.xdec + (size_t)m*Din);
                float v = cacc[r] + bias_c
                        + bfbits2f(xt[0])*wxv_c[0] + bfbits2f(xt[1])*wxv_c[1]
                        + bfbits2f(xt[2])*wxv_c[2] + bfbits2f(xt[3])*wxv_c[3];
                v = fmaxf(v, 0.0f);
                outp[(size_t)m*1024 + ccol] = f2bf(v);
            }
        }
        XSYNC();

        // ---- D3: dec gates (K=1024: w1=W_ih, w2=W_hh from LDS) ----
        {
            const bf16* Ain = bufs[p];
            bf16* hout = bufs[p^1] + Hd;
            bf16* hTw = (t & 1) ? P.hT1 : P.hT0;   // next step reads this buffer
            f32x4 acc[2][2];
#pragma unroll
            for (int mf=0; mf<2; ++mf)
#pragma unroll
                for (int nf=0; nf<2; ++nf) acc[mf][nf] = (f32x4)0.0f;

            s16x8 afr[2], bfr[2];
#pragma unroll
            for (int sl = 0; sl < 16; ++sl){
#pragma unroll
                for (int mf = 0; mf < 2; ++mf)
                    afr[mf] = *reinterpret_cast<const s16x8*>(
                        Ain + (size_t)(arow0 + mf*16)*1024 + sl*32 + quad*8);
#pragma unroll
                for (int nf = 0; nf < 2; ++nf){
                    const int nl = wn*32 + nf*16 + l15;
                    bfr[nf] = *reinterpret_cast<const s16x8*>(
                        &w1_lds[nl*WSTRIDE + sl*32 + quad*8]);
                }
#pragma unroll
                for (int mf = 0; mf < 2; ++mf)
#pragma unroll
                    for (int nf = 0; nf < 2; ++nf)
                        acc[mf][nf] = __builtin_amdgcn_mfma_f32_16x16x32_bf16(
                            afr[mf], bfr[nf], acc[mf][nf], 0, 0, 0);
            }
#pragma unroll
            for (int sl = 0; sl < 16; ++sl){
#pragma unroll
                for (int mf = 0; mf < 2; ++mf)
                    afr[mf] = *reinterpret_cast<const s16x8*>(
                        Ain + (size_t)(arow0 + mf*16)*1024 + Hd + sl*32 + quad*8);
#pragma unroll
                for (int nf = 0; nf < 2; ++nf){
                    const int nl = wn*32 + nf*16 + l15;
                    bfr[nf] = *reinterpret_cast<const s16x8*>(
                        &w2_lds[nl*WSTRIDE + sl*32 + quad*8]);
                }
#pragma unroll
                for (int mf = 0; mf < 2; ++mf)
#pragma unroll
                    for (int nf = 0; nf < 2; ++nf)
                        acc[mf][nf] = __builtin_amdgcn_mfma_f32_16x16x32_bf16(
                            afr[mf], bfr[nf], acc[mf][nf], 0, 0, 0);
            }

#pragma unroll
            for (int mf = 0; mf < 2; ++mf){
                const int mb = bm0 + wm*32 + mf*16 + quad*4;
#pragma unroll
                for (int nf = 0; nf < 2; ++nf){
                    const int n_loc = wn*32 + nf*16 + l15;
                    float hvv[4];
#pragma unroll
                    for (int r = 0; r < 4; ++r){
                        float gv = acc[mf][nf][r] + bias_d[nf];
                        const float gi = __shfl(gv, lbase+0);
                        const float gf = __shfl(gv, lbase+1);
                        const float gg = __shfl(gv, lbase+2);
                        const float go = __shfl(gv, lbase+3);
                        const float cn = sigm(gf)*creg[mf][nf][r] + sigm(gi)*ftanh(gg);
                        creg[mf][nf][r] = cn;
                        hvv[r] = sigm(go)*ftanh(cn);
                    }
                    if ((lane & 3) == 0){
                        const int hcol = hc0 + (n_loc >> 2);
#pragma unroll
                        for (int r = 0; r < 4; ++r)
                            hout[(size_t)(mb+r)*1024 + hcol] = f2bf(hvv[r]);
                        // transposed staging for next step's h_r gather
                        sc_store_b32(hTw + ((hcol*2+0)<<9) + (mb>>1), pack2(hvv[0], hvv[2]));
                        sc_store_b32(hTw + ((hcol*2+1)<<9) + (mb>>1), pack2(hvv[1], hvv[3]));
                    }
                }
            }
        }
        GSYNCL();   // rank0 fence + counter round + L1 inv
    }

    // ---- final pred (t = T-1) ----
    if (wave < 4){
        const int b = b0 + wave;
        const bf16* hb = bufs[Tlen & 1] + Hd + (size_t)b*1024;
        float q0=0.f, q1=0.f, q2=0.f, q3=0.f;
#pragma unroll
        for (int j = 0; j < 8; ++j){
            const float hv = bf2f(hb[lane + j*64]);
            q0 += hv*bfbits2f(owreg[0][j]);
            q1 += hv*bfbits2f(owreg[1][j]);
            q2 += hv*bfbits2f(owreg[2][j]);
            q3 += hv*bfbits2f(owreg[3][j]);
        }
#pragma unroll
        for (int off = 32; off; off >>= 1){
            q0 += __shfl_down(q0, off); q1 += __shfl_down(q1, off);
            q2 += __shfl_down(q2, off); q3 += __shfl_down(q3, off);
        }
        if (lane == 0){
            const size_t o = ((size_t)b*Tlen + (Tlen-1))*Din;
            const float r0 = q0 + ob0, r1 = q1 + ob1;
            const float r2 = q2 + ob2, r3 = q3 + ob3;
            if (f32out){
                float* dp = (float*)P.dout + o;
                dp[0]=r0; dp[1]=r1; dp[2]=r2; dp[3]=r3;
            } else {
                *reinterpret_cast<i32x2*>((bf16*)P.dout + o) = pack4(r0,r1,r2,r3);
            }
        }
    }
}

extern "C" void kernel_launch(void* const* d_in, const int* in_sizes, int n_in,
                              void* d_out, int out_size, void* d_ws, size_t ws_size,
                              hipStream_t stream)
{
    char* ws = (char*)d_ws;
    bf16*  Abuf0   = (bf16*)(ws + OFF_ABUF0);
    bf16*  Abuf1   = (bf16*)(ws + OFF_ABUF1);
    bf16*  hT0     = (bf16*)(ws + OFF_HT0);
    bf16*  hT1     = (bf16*)(ws + OFF_HT1);
    bf16*  attnap  = (bf16*)(ws + OFF_ATTNAP);
    bf16*  xdec    = (bf16*)(ws + OFF_XDEC);
    int*   flag    = (int*)(ws + OFF_FLAG);
    bf16*  combWr  = (bf16*)(ws + OFF_COMBWR);
    bf16*  attnWr  = (bf16*)(ws + OFF_ATTNWR);
    int*   flags   = (int*)(ws + OFF_FLAGS);
    bf16*  wc      = (bf16*)(ws + OFF_WCACHE);
    bf16*  enc_out = (bf16*)(ws + OFF_ENCOUT);

    // layout (ints): xcnt[g] at g*32 (128B lines), gcnt at 256 (own line),
    // grel[g] at 288+g*32, xccmap at 768..1023.
    hipMemsetAsync(flags, 0, 4096, stream);

    probe_kernel<<<1, 256, 0, stream>>>((const unsigned int*)d_in[3], flag);

    Ptrs15 srcs;
    srcs.p[0]=d_in[0];  srcs.p[1]=d_in[2];  srcs.p[2]=d_in[3];  srcs.p[3]=d_in[4];
    srcs.p[4]=d_in[5];  srcs.p[5]=d_in[6];  srcs.p[6]=d_in[7];  srcs.p[7]=d_in[8];
    srcs.p[8]=d_in[9];  srcs.p[9]=d_in[10]; srcs.p[10]=d_in[11];srcs.p[11]=d_in[12];
    srcs.p[12]=d_in[13];srcs.p[13]=d_in[14];srcs.p[14]=d_in[15];
    convert_kernel<<<1024, 256, 0, stream>>>(srcs, flag, wc);

    setup_kernel<<<2048, 256, 0, stream>>>(Abuf0, Abuf1, combWr, attnWr,
                                           wc+WC_CW, wc+WC_AW);

    MegaP P;
    P.input = wc+WC_INPUT; P.eWih = wc+WC_EWIH; P.eWhh = wc+WC_EWHH;
    P.ebih = wc+WC_EBIH;   P.ebhh = wc+WC_EBHH;
    P.aW = wc+WC_AW;  P.ab = wc+WC_AB;  P.cW = wc+WC_CW;  P.cb = wc+WC_CB;
    P.dWih = wc+WC_DWIH; P.dWhh = wc+WC_DWHH; P.dbih = wc+WC_DBIH; P.dbhh = wc+WC_DBHH;
    P.oW = wc+WC_OW;  P.ob = wc+WC_OB;
    P.combWr = combWr; P.attnWr = attnWr;
    P.A0 = Abuf0; P.A1 = Abuf1; P.encout = enc_out; P.attnap = attnap; P.xdec = xdec;
    P.hT0 = hT0; P.hT1 = hT1;
    P.xcnt = flags; P.gcnt = flags + 256; P.grel = flags + 288;
    P.xccmap = flags + 768;
    P.flag = flag; P.dout = d_out;

    mega_kernel<<<NWG, 512, 0, stream>>>(P);
}

// Round 11
// 3246.598 us; speedup vs baseline: 1.0016x; 1.0016x over previous
//
#include <hip/hip_runtime.h>
#include <hip/hip_bf16.h>

#define Bsz   1024
#define Lseq  50
#define Din   4
#define Hd    512
#define Tlen  30
#define NWG   256

typedef __hip_bfloat16 bf16;
typedef short s16x8 __attribute__((ext_vector_type(8)));
typedef short s16x4 __attribute__((ext_vector_type(4)));
typedef float f32x4 __attribute__((ext_vector_type(4)));
typedef int   i32x2 __attribute__((ext_vector_type(2)));

__device__ __forceinline__ float bf2f(bf16 x){ return __bfloat162float(x); }
__device__ __forceinline__ bf16  f2bf(float x){ return __float2bfloat16(x); }
__device__ __forceinline__ float bfbits2f(short u){
    union { unsigned int ui; float f; } v;
    v.ui = ((unsigned int)(unsigned short)u) << 16;
    return v.f;
}
__device__ __forceinline__ short f2bfbits(float x){
    bf16 h = f2bf(x); short s; __builtin_memcpy(&s, &h, 2); return s;
}
__device__ __forceinline__ float sigm(float x){ return 1.0f/(1.0f + __expf(-x)); }
__device__ __forceinline__ float ftanh(float x){
    const float e = __expf(2.0f*x);
    return 1.0f - 2.0f/(e + 1.0f);
}
__device__ __forceinline__ i32x2 pack4(float a, float b, float c, float d){
    i32x2 v;
    v[0] = (int)(unsigned short)f2bfbits(a) | ((int)(unsigned short)f2bfbits(b) << 16);
    v[1] = (int)(unsigned short)f2bfbits(c) | ((int)(unsigned short)f2bfbits(d) << 16);
    return v;
}
__device__ __forceinline__ int pack2(float a, float b){
    return (int)(unsigned short)f2bfbits(a) | ((int)(unsigned short)f2bfbits(b) << 16);
}
// L3-bypass 8B load (sc0 sc1): reads the device coherence point.
__device__ __forceinline__ s16x4 sc_load_b64(const void* p){
    i32x2 v;
    asm volatile("global_load_dwordx2 %0, %1, off sc0 sc1\n\ts_waitcnt vmcnt(0)"
                 : "=v"(v) : "v"(p) : "memory");
    s16x4 r; __builtin_memcpy(&r, &v, 8); return r;
}
// L3-direct 4B store (sc0 sc1).  Drained by __syncthreads' vmcnt(0); the
// rank0 __threadfence in global rounds additionally orders it.
__device__ __forceinline__ void sc_store_b32(void* p, int v){
    asm volatile("global_store_dword %0, %1, off sc0 sc1" :: "v"(p), "v"(v) : "memory");
}

// ---------------- ws layout (bytes) ----------------
#define OFF_ABUF0   (0u)
#define OFF_ABUF1   (2u<<20)
#define OFF_HT0     (4u<<20)
#define OFF_HT1     (5u<<20)
#define OFF_ATTNAP  (8u<<20)
#define OFF_XDEC    (9u<<20)
#define OFF_FLAG    ((9u<<20) + (16u<<10))
#define OFF_COMBWR  ((9u<<20) + (32u<<10))
#define OFF_ATTNWR  ((9u<<20) + (600u<<10))
#define OFF_FLAGS   ((9u<<20) + (704u<<10))
#define OFF_WCACHE  (10u<<20)
#define OFF_ENCOUT  (18u<<20)

// wcache element offsets (bf16 elements), 8-elem aligned per array
#define WC_INPUT 0
#define WC_EWIH  204800
#define WC_EWHH  212992
#define WC_EBIH  1261568
#define WC_EBHH  1263616
#define WC_AW    1265664
#define WC_AB    1291464
#define WC_CW    1291520
#define WC_CB    1555712
#define WC_DWIH  1556224
#define WC_DWHH  2604800
#define WC_DBIH  3653376
#define WC_DBHH  3655424
#define WC_OW    3657472
#define WC_OB    3659520
#define WC_TOTAL 3659524

__device__ __constant__ int WOFF[15] = {
    WC_INPUT, WC_EWIH, WC_EWHH, WC_EBIH, WC_EBHH, WC_AW, WC_AB, WC_CW,
    WC_CB, WC_DWIH, WC_DWHH, WC_DBIH, WC_DBHH, WC_OW, WC_OB };
__device__ __constant__ int WNUM[15] = {
    204800, 8192, 1048576, 2048, 2048, 25800, 50, 264192,
    512, 1048576, 1048576, 2048, 2048, 2048, 4 };

struct Ptrs15 { const void* p[15]; };

__global__ void probe_kernel(const unsigned int* __restrict__ w, int* flag){
    __shared__ int cnt;
    if (threadIdx.x == 0) cnt = 0;
    __syncthreads();
    int c = 0;
    for (int i = threadIdx.x; i < 4096; i += 256){
        unsigned e = (w[i] >> 7) & 0xFFu;
        c += (e >= 0x80u) ? 1 : 0;
    }
    atomicAdd(&cnt, c);
    __syncthreads();
    if (threadIdx.x == 0) *flag = (cnt > 400) ? 1 : 0;
}

__global__ __launch_bounds__(256) void convert_kernel(
    Ptrs15 srcs, const int* __restrict__ flag, bf16* __restrict__ dst)
{
    const int f = *flag;
    for (int idx = blockIdx.x*256 + threadIdx.x; idx < WC_TOTAL;
         idx += gridDim.x*256){
        int a = 0;
#pragma unroll
        for (int j = 1; j < 15; ++j) if (idx >= WOFF[j]) a = j;
        const int local = idx - WOFF[a];
        if (local >= WNUM[a]) continue;
        bf16 v;
        if (f) v = f2bf(((const float*)srcs.p[a])[local]);
        else   v = ((const bf16*)srcs.p[a])[local];
        dst[idx] = v;
    }
}

__global__ __launch_bounds__(256) void setup_kernel(
    bf16* __restrict__ Abuf0, bf16* __restrict__ Abuf1,
    bf16* __restrict__ combWr, bf16* __restrict__ attnWr,
    const bf16* __restrict__ cWc, const bf16* __restrict__ aWc)
{
    const unsigned idx = blockIdx.x*256u + threadIdx.x;
    if (idx < (unsigned)Bsz*Hd){
        const unsigned row = idx >> 9, col = idx & (Hd-1);
        const bf16 z = f2bf(0.0f);
        Abuf0[(size_t)row*1024 + Hd + col] = z;
        Abuf1[(size_t)row*1024 + Hd + col] = z;
    }
    if (idx < (unsigned)Hd*Hd)
        combWr[idx] = cWc[(size_t)(idx >> 9)*(Hd+Din) + Din + (idx & (Hd-1))];
    if (idx < (unsigned)Lseq*Hd)
        attnWr[idx] = aWc[(size_t)(idx >> 9)*(Hd+Din) + Din + (idx & (Hd-1))];
}

struct MegaP {
    const bf16 *input, *eWih, *eWhh, *ebih, *ebhh;
    const bf16 *aW, *ab, *cW, *cb, *dWih, *dWhh, *dbih, *dbhh, *oW, *ob;
    const bf16 *combWr, *attnWr;
    bf16 *A0, *A1, *encout, *attnap, *xdec;
    bf16 *hT0, *hT1;
    int *xcnt, *gcnt, *grel, *xccmap;
    const int *flag;
    void *dout;
};

#define WSTRIDE 536   // LDS weight row stride in shorts (16B aligned, low-conflict)

// ---------------------------------------------------------------------------
// Persistent megakernel v14 = v13 with __launch_bounds__(512, 1).
// v13's diagnosis (R10 counters): VGPR_Count stayed 128 -- launch_bounds
// (512,2) caps the allocator at 128 VGPRs/wave, so the ~80 hoisted VGPRs
// (cwreg/owreg/awx) went to SCRATCH: FETCH +0.6GB, WRITE +57MB, dur +70-100us.
// Occupancy is LDS-bound at 1 WG/CU (160KB/160KB) = 2 waves/SIMD regardless,
// so min-waves=2 bought nothing while forcing spills.  (512,1) raises the
// VGPR budget to 256 with zero occupancy cost.  Everything else is
// byte-identical to v13.
// Verification signal: VGPR_Count ~190-230, FETCH back to ~1.03e6 KB.
// Ledger: poll transport ~0 (v7) · fence storm -180us (v8) · gather ~0 (v6)
// · critical-wave overload -530us (v9) · attnWrT -650us (v11, A/A) ·
// launch_bounds spill trap -80us (v13, fixed here).
// ---------------------------------------------------------------------------
__global__ __launch_bounds__(512, 1) void mega_kernel(MegaP P)
{
    __shared__ short w1_lds[64*WSTRIDE];   // 68,608 B (dec W_ih slice)
    __shared__ short w2_lds[64*WSTRIDE];   // 68,608 B (enc W_hh, then dec W_hh)
    __shared__ short hr_s[4][Hd];          // 4 KB
    __shared__ float ctx_s[2][4][8][64];   // 16 KB
    __shared__ float aw_s[4][64];          // 1 KB
    __shared__ int   xmap_s[NWG];          // 1 KB
    __shared__ int   info_s[2];

    const int wg = blockIdx.x, tid = threadIdx.x;
    const int wave = tid >> 6, lane = tid & 63;
    const int quad = lane >> 4, l15 = lane & 15;
    const int lbase = lane & ~3;
    const int f32out = *P.flag;

    const int grp = wg & 7, rank = wg >> 3;

    int ep = 0, gep = 0;

    // local arrive+wait: one fetch_add + one poller per WG
    auto bar_local = [&](){
        ++ep;
        __syncthreads();                      // drains vmcnt (incl. sc stores)
        if (tid == 0){
            int* c = P.xcnt + grp*32;
            __hip_atomic_fetch_add(c, 1, __ATOMIC_RELAXED, __HIP_MEMORY_SCOPE_SYSTEM);
            while (__hip_atomic_load(c, __ATOMIC_RELAXED, __HIP_MEMORY_SCOPE_SYSTEM) < 32*ep)
                __builtin_amdgcn_s_sleep(2);
        }
        __syncthreads();
    };
    // global arrive+wait.  fmode: 1 = rank0-per-grp fence (grp==XCD verified),
    // 2 = all-WG fence (fallback).
    auto bar_global = [&](int fmode){
        ++ep; ++gep;
        __syncthreads();
        if (tid == 0){
            if (fmode == 2) __threadfence();
            int* c = P.xcnt + grp*32;
            __hip_atomic_fetch_add(c, 1, __ATOMIC_RELAXED, __HIP_MEMORY_SCOPE_SYSTEM);
            if (rank == 0){
                while (__hip_atomic_load(c, __ATOMIC_RELAXED, __HIP_MEMORY_SCOPE_SYSTEM) < 32*ep)
                    __builtin_amdgcn_s_sleep(2);
                if (fmode == 1) __threadfence();   // one L2 writeback per XCD
                __hip_atomic_fetch_add(P.gcnt, 1, __ATOMIC_RELAXED, __HIP_MEMORY_SCOPE_SYSTEM);
                while (__hip_atomic_load(P.gcnt, __ATOMIC_RELAXED, __HIP_MEMORY_SCOPE_SYSTEM) < 8*gep)
                    __builtin_amdgcn_s_sleep(2);
                __hip_atomic_store(P.grel + grp*32, gep, __ATOMIC_RELAXED, __HIP_MEMORY_SCOPE_SYSTEM);
            } else {
                int* r = P.grel + grp*32;
                while (__hip_atomic_load(r, __ATOMIC_RELAXED, __HIP_MEMORY_SCOPE_SYSTEM) < gep)
                    __builtin_amdgcn_s_sleep(2);
            }
        }
        __syncthreads();
    };

    // full fallback: global + L2 invalidate (safe under any WG placement)
    auto GSYNCF = [&](){
        bar_global(2);
        asm volatile("buffer_inv sc0 sc1" ::: "memory");
        __syncthreads();
    };

    // ---- XCD mapping verification ----
    if (tid == 0){
        int xcc = 0;
        asm volatile("s_getreg_b32 %0, hwreg(HW_REG_XCC_ID)" : "=s"(xcc));
        P.xccmap[wg] = xcc & 7;
    }
    GSYNCF();
    if (tid < NWG) xmap_s[tid] = P.xccmap[tid];
    __syncthreads();
    if (tid == 0){
        int ok = 1;
        for (int g = 0; g < 8; ++g){
            const int x0 = xmap_s[g];
            for (int i = 1; i < 32; ++i) ok &= (xmap_s[i*8 + g] == x0);
        }
        info_s[0] = ok;
    }
    __syncthreads();
    const int bal = info_s[0];

    // global sync: rank0-per-XCD fence + counter round + L1-only inv
    auto GSYNCL = [&](){
        if (!bal){ GSYNCF(); return; }
        bar_global(1);
        asm volatile("buffer_inv" ::: "memory");
        __syncthreads();
    };
    // XCD-local sync, L1-only inv
    auto XSYNC = [&](){
        if (!bal){ GSYNCF(); return; }
        bar_local();
        asm volatile("buffer_inv" ::: "memory");
    };

    bf16* bufs[2] = { P.A0, P.A1 };

    // ---- gates tiling: 128 rows x 64 gate-cols per WG ----
    const int bm0 = grp*128, hc0 = rank*16;
    const int wm = wave >> 1, wn = wave & 1;      // 4 x 2 waves (32x32 each)
    const int arow0 = bm0 + wm*32 + l15;

    int ng[2];
#pragma unroll
    for (int nf = 0; nf < 2; ++nf){
        const int n = wn*32 + nf*16 + l15;        // 0..63
        ng[nf] = (n & 3)*Hd + hc0 + (n >> 2);
    }

    // ================= ENCODER =================
    float bias_e[2], wxv_e[2][4];
#pragma unroll
    for (int nf = 0; nf < 2; ++nf){
        bias_e[nf] = bf2f(P.ebih[ng[nf]]) + bf2f(P.ebhh[ng[nf]]);
        const s16x4 t4 = *reinterpret_cast<const s16x4*>(P.eWih + (size_t)ng[nf]*Din);
#pragma unroll
        for (int d = 0; d < 4; ++d) wxv_e[nf][d] = bfbits2f(t4[d]);
    }

    // enc W_hh slice -> w2_lds  (64 local cols x 512 K)
    for (int i = tid; i < 64*64; i += 512){
        const int col = i >> 6, k8 = (i & 63)*8;
        const int g = (col & 3)*Hd + hc0 + (col >> 2);
        const s16x8 v = *reinterpret_cast<const s16x8*>(P.eWhh + (size_t)g*Hd + k8);
        *reinterpret_cast<s16x8*>(&w2_lds[col*WSTRIDE + k8]) = v;
    }
    __syncthreads();

    float creg[2][2][4];
#pragma unroll
    for (int a = 0; a < 2; ++a)
#pragma unroll
        for (int b = 0; b < 2; ++b)
#pragma unroll
            for (int r = 0; r < 4; ++r) creg[a][b][r] = 0.0f;

    for (int t = 0; t < Lseq; ++t){
        const bf16* Ain = bufs[t&1] + Hd;
        bf16* hout = bufs[(t+1)&1] + Hd;

        f32x4 acc[2][2];
#pragma unroll
        for (int mf=0; mf<2; ++mf)
#pragma unroll
            for (int nf=0; nf<2; ++nf) acc[mf][nf] = (f32x4)0.0f;

        s16x8 afr[2], bfr[2];
#pragma unroll
        for (int sl = 0; sl < 16; ++sl){
#pragma unroll
            for (int mf = 0; mf < 2; ++mf)
                afr[mf] = *reinterpret_cast<const s16x8*>(
                    Ain + (size_t)(arow0 + mf*16)*1024 + sl*32 + quad*8);
#pragma unroll
            for (int nf = 0; nf < 2; ++nf){
                const int nl = wn*32 + nf*16 + l15;
                bfr[nf] = *reinterpret_cast<const s16x8*>(
                    &w2_lds[nl*WSTRIDE + sl*32 + quad*8]);
            }
#pragma unroll
            for (int mf = 0; mf < 2; ++mf)
#pragma unroll
                for (int nf = 0; nf < 2; ++nf)
                    acc[mf][nf] = __builtin_amdgcn_mfma_f32_16x16x32_bf16(
                        afr[mf], bfr[nf], acc[mf][nf], 0, 0, 0);
        }

#pragma unroll
        for (int mf = 0; mf < 2; ++mf){
            const int mb = bm0 + wm*32 + mf*16 + quad*4;
            s16x4 xts[4];
#pragma unroll
            for (int r = 0; r < 4; ++r)
                xts[r] = *reinterpret_cast<const s16x4*>(
                    P.input + ((size_t)(mb+r)*Lseq + t)*Din);
#pragma unroll
            for (int nf = 0; nf < 2; ++nf){
                const int n_loc = wn*32 + nf*16 + l15;
                float hvv[4];
#pragma unroll
                for (int r = 0; r < 4; ++r){
                    float gv = acc[mf][nf][r] + bias_e[nf]
                             + bfbits2f(xts[r][0])*wxv_e[nf][0]
                             + bfbits2f(xts[r][1])*wxv_e[nf][1]
                             + bfbits2f(xts[r][2])*wxv_e[nf][2]
                             + bfbits2f(xts[r][3])*wxv_e[nf][3];
                    const float gi = __shfl(gv, lbase+0);
                    const float gf = __shfl(gv, lbase+1);
                    const float gg = __shfl(gv, lbase+2);
                    const float go = __shfl(gv, lbase+3);
                    const float cn = sigm(gf)*creg[mf][nf][r] + sigm(gi)*ftanh(gg);
                    creg[mf][nf][r] = cn;
                    hvv[r] = sigm(go)*ftanh(cn);
                }
                if ((lane & 3) == 0){
                    const int hcol = hc0 + (n_loc >> 2);
#pragma unroll
                    for (int r = 0; r < 4; ++r){
                        const bf16 hb = f2bf(hvv[r]);
                        hout[(size_t)(mb+r)*1024 + hcol] = hb;
                        P.encout[((size_t)(mb+r)*Lseq + t)*Hd + hcol] = hb;
                    }
                    if (t == Lseq-1){
                        // stage h transposed for decoder t=0 (reads hT1)
                        sc_store_b32(P.hT1 + ((hcol*2+0)<<9) + (mb>>1), pack2(hvv[0], hvv[2]));
                        sc_store_b32(P.hT1 + ((hcol*2+1)<<9) + (mb>>1), pack2(hvv[1], hvv[3]));
                    }
                }
            }
        }
        if (t == Lseq-1) GSYNCL(); else XSYNC();
    }

    // ================= DECODER setup =================
    // dec weights -> LDS
    for (int i = tid; i < 64*64; i += 512){
        const int col = i >> 6, k8 = (i & 63)*8;
        const int g = (col & 3)*Hd + hc0 + (col >> 2);
        *reinterpret_cast<s16x8*>(&w1_lds[col*WSTRIDE + k8]) =
            *reinterpret_cast<const s16x8*>(P.dWih + (size_t)g*Hd + k8);
        *reinterpret_cast<s16x8*>(&w2_lds[col*WSTRIDE + k8]) =
            *reinterpret_cast<const s16x8*>(P.dWhh + (size_t)g*Hd + k8);
    }

    float bias_d[2];
#pragma unroll
    for (int nf = 0; nf < 2; ++nf)
        bias_d[nf] = bf2f(P.dbih[ng[nf]]) + bf2f(P.dbhh[ng[nf]]);

    const int b0 = grp*128 + rank*4;
    const int s_uni = b0 >> 9;
    const int p0 = b0 & (Hd-1);

    // enc_out slice -> registers: wave (rr, half) holds row b0+rr, l = half*25+i
    const int rr = wave & 3, half = wave >> 2;
    s16x8 ereg[25];
    {
        const bf16* eb = P.encout + (size_t)(b0 + rr)*Lseq*Hd + lane*8;
#pragma unroll
        for (int i = 0; i < 25; ++i)
            ereg[i] = *reinterpret_cast<const s16x8*>(eb + (size_t)(half*25 + i)*Hd);
    }

    // comb tile: wave covers rows bm0+wave*16, cols ccol
    const int ccol = hc0 + l15;   // 16 comb cols per WG (rank*16..+16)
    float bias_c, wxv_c[4];
    {
        bias_c = bf2f(P.cb[ccol]);
        const s16x4 t4 = *reinterpret_cast<const s16x4*>(P.cW + (size_t)ccol*(Hd+Din));
#pragma unroll
        for (int d = 0; d < 4; ++d) wxv_c[d] = bfbits2f(t4[d]);
    }

    // ---- step-invariant data -> registers (survives the per-round L1 inv) ----
    // D2 comb weight fragments: 16 x s16x8 = 64 VGPRs
    s16x8 cwreg[16];
#pragma unroll
    for (int kk = 0; kk < 16; ++kk)
        cwreg[kk] = *reinterpret_cast<const s16x8*>(
            P.combWr + (size_t)ccol*Hd + kk*32 + quad*8);
    // pred oW rows at this lane's stride-64 positions: 4 x s16x8 = 16 VGPRs
    s16x8 owreg[4];
#pragma unroll
    for (int r2 = 0; r2 < 4; ++r2){
#pragma unroll
        for (int j = 0; j < 8; ++j){
            short s; __builtin_memcpy(&s, P.oW + r2*Hd + lane + j*64, 2);
            owreg[r2][j] = s;
        }
    }
    // attention x-part weights + bias for this lane (guarded: aW has Lseq rows)
    float abv = 0.0f, awx[4] = {0.f,0.f,0.f,0.f};
    if (lane < Lseq){
        abv = bf2f(P.ab[lane]);
        const s16x4 t4 = *reinterpret_cast<const s16x4*>(P.aW + (size_t)lane*(Hd+Din));
#pragma unroll
        for (int d = 0; d < 4; ++d) awx[d] = bfbits2f(t4[d]);
    }
    const float ob0 = bf2f(P.ob[0]), ob1 = bf2f(P.ob[1]);
    const float ob2 = bf2f(P.ob[2]), ob3 = bf2f(P.ob[3]);
    __syncthreads();  // LDS fills complete

    for (int t = 0; t < Tlen; ++t){
        const int p = t & 1;
        const bf16* hprev = bufs[p] + Hd;

        // ---- D1: hr staging (coalesced from transposed hT) + pred(t-1) + attention ----
        {
            const bf16* hTr = (t & 1) ? P.hT0 : P.hT1;   // written prev step / by encoder
            const int q = tid >> 7;                      // 0..3 -> hr row
            const int i0 = (tid & 127) << 2;             // 0..508 step 4
            const s16x4 hv = sc_load_b64(hTr + (size_t)(((p0 + q)*2 + s_uni)<<9) + i0);
            *reinterpret_cast<s16x4*>(&hr_s[q][i0]) = hv;
        }
        __syncthreads();

        if (wave < 4){
            const int b = b0 + wave;
            float x0, x1, x2, x3;
            if (t == 0){
                const bf16* xp = P.input + ((size_t)b*Lseq + (Lseq-1))*Din;
                x0 = bf2f(xp[0]); x1 = bf2f(xp[1]); x2 = bf2f(xp[2]); x3 = bf2f(xp[3]);
            } else {
                float q0=0.f, q1=0.f, q2=0.f, q3=0.f;
                const bf16* hb = hprev + (size_t)b*1024;
#pragma unroll
                for (int j = 0; j < 8; ++j){
                    const float hv = bf2f(hb[lane + j*64]);
                    q0 += hv*bfbits2f(owreg[0][j]);
                    q1 += hv*bfbits2f(owreg[1][j]);
                    q2 += hv*bfbits2f(owreg[2][j]);
                    q3 += hv*bfbits2f(owreg[3][j]);
                }
#pragma unroll
                for (int off = 32; off; off >>= 1){
                    q0 += __shfl_down(q0, off); q1 += __shfl_down(q1, off);
                    q2 += __shfl_down(q2, off); q3 += __shfl_down(q3, off);
                }
                x0 = __shfl(q0,0) + ob0;
                x1 = __shfl(q1,0) + ob1;
                x2 = __shfl(q2,0) + ob2;
                x3 = __shfl(q3,0) + ob3;
                if (lane == 0){
                    const size_t o = ((size_t)b*Tlen + (t-1))*Din;
                    if (f32out){
                        float* dp = (float*)P.dout + o;
                        dp[0]=x0; dp[1]=x1; dp[2]=x2; dp[3]=x3;
                    } else {
                        *reinterpret_cast<i32x2*>((bf16*)P.dout + o) = pack4(x0,x1,x2,x3);
                    }
                }
            }
            if (lane == 0)
                *reinterpret_cast<i32x2*>(P.xdec + (size_t)b*Din) = pack4(x0,x1,x2,x3);

            float logit = -3.0e38f;
            if (lane < Lseq){
                float a0 = abv + x0*awx[0] + x1*awx[1] + x2*awx[2] + x3*awx[3];
                float a1 = 0.f, a2 = 0.f, a3 = 0.f;
                const bf16* wr = P.attnWr + (size_t)lane*Hd;
                for (int j = 0; j < Hd; j += 16){
                    float t4[4] = {0.f,0.f,0.f,0.f};
#pragma unroll
                    for (int q = 0; q < 4; ++q){
                        const s16x4 hw = *reinterpret_cast<const s16x4*>(&hr_s[wave][j + q*4]);
                        const s16x4 wv = *reinterpret_cast<const s16x4*>(wr + j + q*4);
                        t4[q] = bfbits2f(hw[0])*bfbits2f(wv[0]) + bfbits2f(hw[1])*bfbits2f(wv[1])
                              + bfbits2f(hw[2])*bfbits2f(wv[2]) + bfbits2f(hw[3])*bfbits2f(wv[3]);
                    }
                    a0 += t4[0]; a1 += t4[1]; a2 += t4[2]; a3 += t4[3];
                }
                logit = (a0 + a1) + (a2 + a3);
            }
            float mx = logit;
#pragma unroll
            for (int off = 32; off; off >>= 1) mx = fmaxf(mx, __shfl_xor(mx, off));
            const float e = (lane < Lseq) ? __expf(logit - mx) : 0.0f;
            float se = e;
#pragma unroll
            for (int off = 32; off; off >>= 1) se += __shfl_xor(se, off);
            aw_s[wave][lane] = e / se;
        }
        __syncthreads();

        // context entirely from registers
        {
            float acc8[8] = {0.f,0.f,0.f,0.f,0.f,0.f,0.f,0.f};
#pragma unroll
            for (int i = 0; i < 25; ++i){
                const float w = aw_s[rr][half*25 + i];
#pragma unroll
                for (int q = 0; q < 8; ++q) acc8[q] += w * bfbits2f(ereg[i][q]);
            }
#pragma unroll
            for (int q = 0; q < 8; ++q) ctx_s[half][rr][q][lane] = acc8[q];
        }
        __syncthreads();

        if (wave < 4){
            const int b = b0 + wave;
            s16x8 ov;
#pragma unroll
            for (int q = 0; q < 8; ++q)
                ov[q] = f2bfbits(ctx_s[0][wave][q][lane] + ctx_s[1][wave][q][lane]);
            *reinterpret_cast<s16x8*>(P.attnap + (size_t)b*Hd + lane*8) = ov;
        }
        XSYNC();

        // ---- D2: comb GEMM (128 rows x 16 cols per WG), weights in VGPRs ----
        {
            f32x4 cacc = (f32x4)0.0f;
            const bf16* Ab = P.attnap + (size_t)(bm0 + wave*16 + l15)*Hd + quad*8;
#pragma unroll
            for (int kk = 0; kk < 16; ++kk){
                const s16x8 afr2 = *reinterpret_cast<const s16x8*>(Ab + kk*32);
                cacc = __builtin_amdgcn_mfma_f32_16x16x32_bf16(afr2, cwreg[kk], cacc, 0, 0, 0);
            }
            bf16* outp = bufs[p];
#pragma unroll
            for (int r = 0; r < 4; ++r){
                const int m = bm0 + wave*16 + quad*4 + r;
                const s16x4 xt = *reinterpret_cast<const s16x4*>(P.xdec + (size_t)m*Din);
                float v = cacc[r] + bias_c
                        + bfbits2f(xt[0])*wxv_c[0] + bfbits2f(xt[1])*wxv_c[1]
                        + bfbits2f(xt[2])*wxv_c[2] + bfbits2f(xt[3])*wxv_c[3];
                v = fmaxf(v, 0.0f);
                outp[(size_t)m*1024 + ccol] = f2bf(v);
            }
        }
        XSYNC();

        // ---- D3: dec gates (K=1024: w1=W_ih, w2=W_hh from LDS) ----
        {
            const bf16* Ain = bufs[p];
            bf16* hout = bufs[p^1] + Hd;
            bf16* hTw = (t & 1) ? P.hT1 : P.hT0;   // next step reads this buffer
            f32x4 acc[2][2];
#pragma unroll
            for (int mf=0; mf<2; ++mf)
#pragma unroll
                for (int nf=0; nf<2; ++nf) acc[mf][nf] = (f32x4)0.0f;

            s16x8 afr[2], bfr[2];
#pragma unroll
            for (int sl = 0; sl < 16; ++sl){
#pragma unroll
                for (int mf = 0; mf < 2; ++mf)
                    afr[mf] = *reinterpret_cast<const s16x8*>(
                        Ain + (size_t)(arow0 + mf*16)*1024 + sl*32 + quad*8);
#pragma unroll
                for (int nf = 0; nf < 2; ++nf){
                    const int nl = wn*32 + nf*16 + l15;
                    bfr[nf] = *reinterpret_cast<const s16x8*>(
                        &w1_lds[nl*WSTRIDE + sl*32 + quad*8]);
                }
#pragma unroll
                for (int mf = 0; mf < 2; ++mf)
#pragma unroll
                    for (int nf = 0; nf < 2; ++nf)
                        acc[mf][nf] = __builtin_amdgcn_mfma_f32_16x16x32_bf16(
                            afr[mf], bfr[nf], acc[mf][nf], 0, 0, 0);
            }
#pragma unroll
            for (int sl = 0; sl < 16; ++sl){
#pragma unroll
                for (int mf = 0; mf < 2; ++mf)
                    afr[mf] = *reinterpret_cast<const s16x8*>(
                        Ain + (size_t)(arow0 + mf*16)*1024 + Hd + sl*32 + quad*8);
#pragma unroll
                for (int nf = 0; nf < 2; ++nf){
                    const int nl = wn*32 + nf*16 + l15;
                    bfr[nf] = *reinterpret_cast<const s16x8*>(
                        &w2_lds[nl*WSTRIDE + sl*32 + quad*8]);
                }
#pragma unroll
                for (int mf = 0; mf < 2; ++mf)
#pragma unroll
                    for (int nf = 0; nf < 2; ++nf)
                        acc[mf][nf] = __builtin_amdgcn_mfma_f32_16x16x32_bf16(
                            afr[mf], bfr[nf], acc[mf][nf], 0, 0, 0);
            }

#pragma unroll
            for (int mf = 0; mf < 2; ++mf){
                const int mb = bm0 + wm*32 + mf*16 + quad*4;
#pragma unroll
                for (int nf = 0; nf < 2; ++nf){
                    const int n_loc = wn*32 + nf*16 + l15;
                    float hvv[4];
#pragma unroll
                    for (int r = 0; r < 4; ++r){
                        float gv = acc[mf][nf][r] + bias_d[nf];
                        const float gi = __shfl(gv, lbase+0);
                        const float gf = __shfl(gv, lbase+1);
                        const float gg = __shfl(gv, lbase+2);
                        const float go = __shfl(gv, lbase+3);
                        const float cn = sigm(gf)*creg[mf][nf][r] + sigm(gi)*ftanh(gg);
                        creg[mf][nf][r] = cn;
                        hvv[r] = sigm(go)*ftanh(cn);
                    }
                    if ((lane & 3) == 0){
                        const int hcol = hc0 + (n_loc >> 2);
#pragma unroll
                        for (int r = 0; r < 4; ++r)
                            hout[(size_t)(mb+r)*1024 + hcol] = f2bf(hvv[r]);
                        // transposed staging for next step's h_r gather
                        sc_store_b32(hTw + ((hcol*2+0)<<9) + (mb>>1), pack2(hvv[0], hvv[2]));
                        sc_store_b32(hTw + ((hcol*2+1)<<9) + (mb>>1), pack2(hvv[1], hvv[3]));
                    }
                }
            }
        }
        GSYNCL();   // rank0 fence + counter round + L1 inv
    }

    // ---- final pred (t = T-1) ----
    if (wave < 4){
        const int b = b0 + wave;
        const bf16* hb = bufs[Tlen & 1] + Hd + (size_t)b*1024;
        float q0=0.f, q1=0.f, q2=0.f, q3=0.f;
#pragma unroll
        for (int j = 0; j < 8; ++j){
            const float hv = bf2f(hb[lane + j*64]);
            q0 += hv*bfbits2f(owreg[0][j]);
            q1 += hv*bfbits2f(owreg[1][j]);
            q2 += hv*bfbits2f(owreg[2][j]);
            q3 += hv*bfbits2f(owreg[3][j]);
        }
#pragma unroll
        for (int off = 32; off; off >>= 1){
            q0 += __shfl_down(q0, off); q1 += __shfl_down(q1, off);
            q2 += __shfl_down(q2, off); q3 += __shfl_down(q3, off);
        }
        if (lane == 0){
            const size_t o = ((size_t)b*Tlen + (Tlen-1))*Din;
            const float r0 = q0 + ob0, r1 = q1 + ob1;
            const float r2 = q2 + ob2, r3 = q3 + ob3;
            if (f32out){
                float* dp = (float*)P.dout + o;
                dp[0]=r0; dp[1]=r1; dp[2]=r2; dp[3]=r3;
            } else {
                *reinterpret_cast<i32x2*>((bf16*)P.dout + o) = pack4(r0,r1,r2,r3);
            }
        }
    }
}

extern "C" void kernel_launch(void* const* d_in, const int* in_sizes, int n_in,
                              void* d_out, int out_size, void* d_ws, size_t ws_size,
                              hipStream_t stream)
{
    char* ws = (char*)d_ws;
    bf16*  Abuf0   = (bf16*)(ws + OFF_ABUF0);
    bf16*  Abuf1   = (bf16*)(ws + OFF_ABUF1);
    bf16*  hT0     = (bf16*)(ws + OFF_HT0);
    bf16*  hT1     = (bf16*)(ws + OFF_HT1);
    bf16*  attnap  = (bf16*)(ws + OFF_ATTNAP);
    bf16*  xdec    = (bf16*)(ws + OFF_XDEC);
    int*   flag    = (int*)(ws + OFF_FLAG);
    bf16*  combWr  = (bf16*)(ws + OFF_COMBWR);
    bf16*  attnWr  = (bf16*)(ws + OFF_ATTNWR);
    int*   flags   = (int*)(ws + OFF_FLAGS);
    bf16*  wc      = (bf16*)(ws + OFF_WCACHE);
    bf16*  enc_out = (bf16*)(ws + OFF_ENCOUT);

    // layout (ints): xcnt[g] at g*32 (128B lines), gcnt at 256 (own line),
    // grel[g] at 288+g*32, xccmap at 768..1023.
    hipMemsetAsync(flags, 0, 4096, stream);

    probe_kernel<<<1, 256, 0, stream>>>((const unsigned int*)d_in[3], flag);

    Ptrs15 srcs;
    srcs.p[0]=d_in[0];  srcs.p[1]=d_in[2];  srcs.p[2]=d_in[3];  srcs.p[3]=d_in[4];
    srcs.p[4]=d_in[5];  srcs.p[5]=d_in[6];  srcs.p[6]=d_in[7];  srcs.p[7]=d_in[8];
    srcs.p[8]=d_in[9];  srcs.p[9]=d_in[10]; srcs.p[10]=d_in[11];srcs.p[11]=d_in[12];
    srcs.p[12]=d_in[13];srcs.p[13]=d_in[14];srcs.p[14]=d_in[15];
    convert_kernel<<<1024, 256, 0, stream>>>(srcs, flag, wc);

    setup_kernel<<<2048, 256, 0, stream>>>(Abuf0, Abuf1, combWr, attnWr,
                                           wc+WC_CW, wc+WC_AW);

    MegaP P;
    P.input = wc+WC_INPUT; P.eWih = wc+WC_EWIH; P.eWhh = wc+WC_EWHH;
    P.ebih = wc+WC_EBIH;   P.ebhh = wc+WC_EBHH;
    P.aW = wc+WC_AW;  P.ab = wc+WC_AB;  P.cW = wc+WC_CW;  P.cb = wc+WC_CB;
    P.dWih = wc+WC_DWIH; P.dWhh = wc+WC_DWHH; P.dbih = wc+WC_DBIH; P.dbhh = wc+WC_DBHH;
    P.oW = wc+WC_OW;  P.ob = wc+WC_OB;
    P.combWr = combWr; P.attnWr = attnWr;
    P.A0 = Abuf0; P.A1 = Abuf1; P.encout = enc_out; P.attnap = attnap; P.xdec = xdec;
    P.hT0 = hT0; P.hT1 = hT1;
    P.xcnt = flags; P.gcnt = flags + 256; P.grel = flags + 288;
    P.xccmap = flags + 768;
    P.flag = flag; P.dout = d_out;

    mega_kernel<<<NWG, 512, 0, stream>>>(P);
}

// Round 12
// 3145.105 us; speedup vs baseline: 1.0340x; 1.0323x over previous
//
#include <hip/hip_runtime.h>
#include <hip/hip_bf16.h>

#define Bsz   1024
#define Lseq  50
#define Din   4
#define Hd    512
#define Tlen  30
#define NWG   256

typedef __hip_bfloat16 bf16;
typedef short s16x8 __attribute__((ext_vector_type(8)));
typedef short s16x4 __attribute__((ext_vector_type(4)));
typedef float f32x4 __attribute__((ext_vector_type(4)));
typedef int   i32x2 __attribute__((ext_vector_type(2)));

__device__ __forceinline__ float bf2f(bf16 x){ return __bfloat162float(x); }
__device__ __forceinline__ bf16  f2bf(float x){ return __float2bfloat16(x); }
__device__ __forceinline__ float bfbits2f(short u){
    union { unsigned int ui; float f; } v;
    v.ui = ((unsigned int)(unsigned short)u) << 16;
    return v.f;
}
__device__ __forceinline__ short f2bfbits(float x){
    bf16 h = f2bf(x); short s; __builtin_memcpy(&s, &h, 2); return s;
}
__device__ __forceinline__ float sigm(float x){ return 1.0f/(1.0f + __expf(-x)); }
__device__ __forceinline__ float ftanh(float x){
    const float e = __expf(2.0f*x);
    return 1.0f - 2.0f/(e + 1.0f);
}
__device__ __forceinline__ i32x2 pack4(float a, float b, float c, float d){
    i32x2 v;
    v[0] = (int)(unsigned short)f2bfbits(a) | ((int)(unsigned short)f2bfbits(b) << 16);
    v[1] = (int)(unsigned short)f2bfbits(c) | ((int)(unsigned short)f2bfbits(d) << 16);
    return v;
}
__device__ __forceinline__ int pack2(float a, float b){
    return (int)(unsigned short)f2bfbits(a) | ((int)(unsigned short)f2bfbits(b) << 16);
}
// L3-bypass 8B load (sc0 sc1): reads the device coherence point.
__device__ __forceinline__ s16x4 sc_load_b64(const void* p){
    i32x2 v;
    asm volatile("global_load_dwordx2 %0, %1, off sc0 sc1\n\ts_waitcnt vmcnt(0)"
                 : "=v"(v) : "v"(p) : "memory");
    s16x4 r; __builtin_memcpy(&r, &v, 8); return r;
}
// L3-direct 4B store (sc0 sc1).  Drained by __syncthreads' vmcnt(0); the
// rank0 __threadfence in global rounds additionally orders it.
__device__ __forceinline__ void sc_store_b32(void* p, int v){
    asm volatile("global_store_dword %0, %1, off sc0 sc1" :: "v"(p), "v"(v) : "memory");
}

// ---------------- ws layout (bytes) ----------------
#define OFF_ABUF0   (0u)
#define OFF_ABUF1   (2u<<20)
#define OFF_HT0     (4u<<20)
#define OFF_HT1     (5u<<20)
#define OFF_ATTNAP  (8u<<20)
#define OFF_XDEC    (9u<<20)
#define OFF_FLAG    ((9u<<20) + (16u<<10))
#define OFF_COMBWR  ((9u<<20) + (32u<<10))
#define OFF_ATTNWR  ((9u<<20) + (600u<<10))
#define OFF_FLAGS   ((9u<<20) + (704u<<10))
#define OFF_WCACHE  (10u<<20)
#define OFF_ENCOUT  (18u<<20)

// wcache element offsets (bf16 elements), 8-elem aligned per array
#define WC_INPUT 0
#define WC_EWIH  204800
#define WC_EWHH  212992
#define WC_EBIH  1261568
#define WC_EBHH  1263616
#define WC_AW    1265664
#define WC_AB    1291464
#define WC_CW    1291520
#define WC_CB    1555712
#define WC_DWIH  1556224
#define WC_DWHH  2604800
#define WC_DBIH  3653376
#define WC_DBHH  3655424
#define WC_OW    3657472
#define WC_OB    3659520
#define WC_TOTAL 3659524

__device__ __constant__ int WOFF[15] = {
    WC_INPUT, WC_EWIH, WC_EWHH, WC_EBIH, WC_EBHH, WC_AW, WC_AB, WC_CW,
    WC_CB, WC_DWIH, WC_DWHH, WC_DBIH, WC_DBHH, WC_OW, WC_OB };
__device__ __constant__ int WNUM[15] = {
    204800, 8192, 1048576, 2048, 2048, 25800, 50, 264192,
    512, 1048576, 1048576, 2048, 2048, 2048, 4 };

struct Ptrs15 { const void* p[15]; };

__global__ void probe_kernel(const unsigned int* __restrict__ w, int* flag){
    __shared__ int cnt;
    if (threadIdx.x == 0) cnt = 0;
    __syncthreads();
    int c = 0;
    for (int i = threadIdx.x; i < 4096; i += 256){
        unsigned e = (w[i] >> 7) & 0xFFu;
        c += (e >= 0x80u) ? 1 : 0;
    }
    atomicAdd(&cnt, c);
    __syncthreads();
    if (threadIdx.x == 0) *flag = (cnt > 400) ? 1 : 0;
}

__global__ __launch_bounds__(256) void convert_kernel(
    Ptrs15 srcs, const int* __restrict__ flag, bf16* __restrict__ dst)
{
    const int f = *flag;
    for (int idx = blockIdx.x*256 + threadIdx.x; idx < WC_TOTAL;
         idx += gridDim.x*256){
        int a = 0;
#pragma unroll
        for (int j = 1; j < 15; ++j) if (idx >= WOFF[j]) a = j;
        const int local = idx - WOFF[a];
        if (local >= WNUM[a]) continue;
        bf16 v;
        if (f) v = f2bf(((const float*)srcs.p[a])[local]);
        else   v = ((const bf16*)srcs.p[a])[local];
        dst[idx] = v;
    }
}

__global__ __launch_bounds__(256) void setup_kernel(
    bf16* __restrict__ Abuf0, bf16* __restrict__ Abuf1,
    bf16* __restrict__ combWr, bf16* __restrict__ attnWr,
    const bf16* __restrict__ cWc, const bf16* __restrict__ aWc)
{
    const unsigned idx = blockIdx.x*256u + threadIdx.x;
    if (idx < (unsigned)Bsz*Hd){
        const unsigned row = idx >> 9, col = idx & (Hd-1);
        const bf16 z = f2bf(0.0f);
        Abuf0[(size_t)row*1024 + Hd + col] = z;
        Abuf1[(size_t)row*1024 + Hd + col] = z;
    }
    if (idx < (unsigned)Hd*Hd)
        combWr[idx] = cWc[(size_t)(idx >> 9)*(Hd+Din) + Din + (idx & (Hd-1))];
    if (idx < (unsigned)Lseq*Hd)
        attnWr[idx] = aWc[(size_t)(idx >> 9)*(Hd+Din) + Din + (idx & (Hd-1))];
}

struct MegaP {
    const bf16 *input, *eWih, *eWhh, *ebih, *ebhh;
    const bf16 *aW, *ab, *cW, *cb, *dWih, *dWhh, *dbih, *dbhh, *oW, *ob;
    const bf16 *combWr, *attnWr;
    bf16 *A0, *A1, *encout, *attnap, *xdec;
    bf16 *hT0, *hT1;
    int *xcnt, *gcnt, *grel, *xccmap;
    const int *flag;
    void *dout;
};

#define WSTRIDE 536   // LDS weight row stride in shorts (16B aligned, low-conflict)

// ---------------------------------------------------------------------------
// FINAL: Persistent megakernel v15 = exact v12/v8 (confirmed best: 3154us,
// reproduced across two containers: 3156.4 R5, 3153.9 R9).
// R11 closed the register-hoist arc: with a 512-thread (8-wave) workgroup the
// backend clamps to 2 waves/SIMD regardless of launch_bounds, and the unified
// VGPR/AGPR budget (256/wave incl. MFMA accumulators) leaves no room -- the
// hoist spills to scratch no matter what (VGPR pinned 128, FETCH +0.6GB).
// Session ledger (A/B-tested): fence storm -180us (v8) · counter barrier ~0
// (v7) · hT-transposed gather ~0 (v6) · rebalance -530us (v9, reverted) ·
// attnWrT -650us (v11, A/A-confirmed harmful) · reg-hoist infeasible
// (v13/v14, spills) · split-barrier untestable (v10, container failures).
// Not a HW roofline (MfmaUtil 3.3%, HBM 5.3%): the floor is the algorithm's
// ~140 sequential sync rounds (30 grid-wide) at 1 WG/CU.  Net: 3504 -> 3154.
// ---------------------------------------------------------------------------
__global__ __launch_bounds__(512, 2) void mega_kernel(MegaP P)
{
    __shared__ short w1_lds[64*WSTRIDE];   // 68,608 B (dec W_ih slice)
    __shared__ short w2_lds[64*WSTRIDE];   // 68,608 B (enc W_hh, then dec W_hh)
    __shared__ short hr_s[4][Hd];          // 4 KB
    __shared__ float ctx_s[2][4][8][64];   // 16 KB
    __shared__ float aw_s[4][64];          // 1 KB
    __shared__ int   xmap_s[NWG];          // 1 KB
    __shared__ int   info_s[2];

    const int wg = blockIdx.x, tid = threadIdx.x;
    const int wave = tid >> 6, lane = tid & 63;
    const int quad = lane >> 4, l15 = lane & 15;
    const int lbase = lane & ~3;
    const int f32out = *P.flag;

    const int grp = wg & 7, rank = wg >> 3;

    int ep = 0, gep = 0;

    // local arrive+wait: one fetch_add + one poller per WG
    auto bar_local = [&](){
        ++ep;
        __syncthreads();                      // drains vmcnt (incl. sc stores)
        if (tid == 0){
            int* c = P.xcnt + grp*32;
            __hip_atomic_fetch_add(c, 1, __ATOMIC_RELAXED, __HIP_MEMORY_SCOPE_SYSTEM);
            while (__hip_atomic_load(c, __ATOMIC_RELAXED, __HIP_MEMORY_SCOPE_SYSTEM) < 32*ep)
                __builtin_amdgcn_s_sleep(2);
        }
        __syncthreads();
    };
    // global arrive+wait.  fmode: 1 = rank0-per-grp fence (grp==XCD verified),
    // 2 = all-WG fence (fallback).
    auto bar_global = [&](int fmode){
        ++ep; ++gep;
        __syncthreads();
        if (tid == 0){
            if (fmode == 2) __threadfence();
            int* c = P.xcnt + grp*32;
            __hip_atomic_fetch_add(c, 1, __ATOMIC_RELAXED, __HIP_MEMORY_SCOPE_SYSTEM);
            if (rank == 0){
                while (__hip_atomic_load(c, __ATOMIC_RELAXED, __HIP_MEMORY_SCOPE_SYSTEM) < 32*ep)
                    __builtin_amdgcn_s_sleep(2);
                if (fmode == 1) __threadfence();   // one L2 writeback per XCD
                __hip_atomic_fetch_add(P.gcnt, 1, __ATOMIC_RELAXED, __HIP_MEMORY_SCOPE_SYSTEM);
                while (__hip_atomic_load(P.gcnt, __ATOMIC_RELAXED, __HIP_MEMORY_SCOPE_SYSTEM) < 8*gep)
                    __builtin_amdgcn_s_sleep(2);
                __hip_atomic_store(P.grel + grp*32, gep, __ATOMIC_RELAXED, __HIP_MEMORY_SCOPE_SYSTEM);
            } else {
                int* r = P.grel + grp*32;
                while (__hip_atomic_load(r, __ATOMIC_RELAXED, __HIP_MEMORY_SCOPE_SYSTEM) < gep)
                    __builtin_amdgcn_s_sleep(2);
            }
        }
        __syncthreads();
    };

    // full fallback: global + L2 invalidate (safe under any WG placement)
    auto GSYNCF = [&](){
        bar_global(2);
        asm volatile("buffer_inv sc0 sc1" ::: "memory");
        __syncthreads();
    };

    // ---- XCD mapping verification ----
    if (tid == 0){
        int xcc = 0;
        asm volatile("s_getreg_b32 %0, hwreg(HW_REG_XCC_ID)" : "=s"(xcc));
        P.xccmap[wg] = xcc & 7;
    }
    GSYNCF();
    if (tid < NWG) xmap_s[tid] = P.xccmap[tid];
    __syncthreads();
    if (tid == 0){
        int ok = 1;
        for (int g = 0; g < 8; ++g){
            const int x0 = xmap_s[g];
            for (int i = 1; i < 32; ++i) ok &= (xmap_s[i*8 + g] == x0);
        }
        info_s[0] = ok;
    }
    __syncthreads();
    const int bal = info_s[0];

    // global sync: rank0-per-XCD fence + counter round + L1-only inv
    auto GSYNCL = [&](){
        if (!bal){ GSYNCF(); return; }
        bar_global(1);
        asm volatile("buffer_inv" ::: "memory");
        __syncthreads();
    };
    // XCD-local sync, L1-only inv
    auto XSYNC = [&](){
        if (!bal){ GSYNCF(); return; }
        bar_local();
        asm volatile("buffer_inv" ::: "memory");
    };

    bf16* bufs[2] = { P.A0, P.A1 };

    // ---- gates tiling: 128 rows x 64 gate-cols per WG ----
    const int bm0 = grp*128, hc0 = rank*16;
    const int wm = wave >> 1, wn = wave & 1;      // 4 x 2 waves (32x32 each)
    const int arow0 = bm0 + wm*32 + l15;

    int ng[2];
#pragma unroll
    for (int nf = 0; nf < 2; ++nf){
        const int n = wn*32 + nf*16 + l15;        // 0..63
        ng[nf] = (n & 3)*Hd + hc0 + (n >> 2);
    }

    // ================= ENCODER =================
    float bias_e[2], wxv_e[2][4];
#pragma unroll
    for (int nf = 0; nf < 2; ++nf){
        bias_e[nf] = bf2f(P.ebih[ng[nf]]) + bf2f(P.ebhh[ng[nf]]);
        const s16x4 t4 = *reinterpret_cast<const s16x4*>(P.eWih + (size_t)ng[nf]*Din);
#pragma unroll
        for (int d = 0; d < 4; ++d) wxv_e[nf][d] = bfbits2f(t4[d]);
    }

    // enc W_hh slice -> w2_lds  (64 local cols x 512 K)
    for (int i = tid; i < 64*64; i += 512){
        const int col = i >> 6, k8 = (i & 63)*8;
        const int g = (col & 3)*Hd + hc0 + (col >> 2);
        const s16x8 v = *reinterpret_cast<const s16x8*>(P.eWhh + (size_t)g*Hd + k8);
        *reinterpret_cast<s16x8*>(&w2_lds[col*WSTRIDE + k8]) = v;
    }
    __syncthreads();

    float creg[2][2][4];
#pragma unroll
    for (int a = 0; a < 2; ++a)
#pragma unroll
        for (int b = 0; b < 2; ++b)
#pragma unroll
            for (int r = 0; r < 4; ++r) creg[a][b][r] = 0.0f;

    for (int t = 0; t < Lseq; ++t){
        const bf16* Ain = bufs[t&1] + Hd;
        bf16* hout = bufs[(t+1)&1] + Hd;

        f32x4 acc[2][2];
#pragma unroll
        for (int mf=0; mf<2; ++mf)
#pragma unroll
            for (int nf=0; nf<2; ++nf) acc[mf][nf] = (f32x4)0.0f;

        s16x8 afr[2], bfr[2];
#pragma unroll
        for (int sl = 0; sl < 16; ++sl){
#pragma unroll
            for (int mf = 0; mf < 2; ++mf)
                afr[mf] = *reinterpret_cast<const s16x8*>(
                    Ain + (size_t)(arow0 + mf*16)*1024 + sl*32 + quad*8);
#pragma unroll
            for (int nf = 0; nf < 2; ++nf){
                const int nl = wn*32 + nf*16 + l15;
                bfr[nf] = *reinterpret_cast<const s16x8*>(
                    &w2_lds[nl*WSTRIDE + sl*32 + quad*8]);
            }
#pragma unroll
            for (int mf = 0; mf < 2; ++mf)
#pragma unroll
                for (int nf = 0; nf < 2; ++nf)
                    acc[mf][nf] = __builtin_amdgcn_mfma_f32_16x16x32_bf16(
                        afr[mf], bfr[nf], acc[mf][nf], 0, 0, 0);
        }

#pragma unroll
        for (int mf = 0; mf < 2; ++mf){
            const int mb = bm0 + wm*32 + mf*16 + quad*4;
            s16x4 xts[4];
#pragma unroll
            for (int r = 0; r < 4; ++r)
                xts[r] = *reinterpret_cast<const s16x4*>(
                    P.input + ((size_t)(mb+r)*Lseq + t)*Din);
#pragma unroll
            for (int nf = 0; nf < 2; ++nf){
                const int n_loc = wn*32 + nf*16 + l15;
                float hvv[4];
#pragma unroll
                for (int r = 0; r < 4; ++r){
                    float gv = acc[mf][nf][r] + bias_e[nf]
                             + bfbits2f(xts[r][0])*wxv_e[nf][0]
                             + bfbits2f(xts[r][1])*wxv_e[nf][1]
                             + bfbits2f(xts[r][2])*wxv_e[nf][2]
                             + bfbits2f(xts[r][3])*wxv_e[nf][3];
                    const float gi = __shfl(gv, lbase+0);
                    const float gf = __shfl(gv, lbase+1);
                    const float gg = __shfl(gv, lbase+2);
                    const float go = __shfl(gv, lbase+3);
                    const float cn = sigm(gf)*creg[mf][nf][r] + sigm(gi)*ftanh(gg);
                    creg[mf][nf][r] = cn;
                    hvv[r] = sigm(go)*ftanh(cn);
                }
                if ((lane & 3) == 0){
                    const int hcol = hc0 + (n_loc >> 2);
#pragma unroll
                    for (int r = 0; r < 4; ++r){
                        const bf16 hb = f2bf(hvv[r]);
                        hout[(size_t)(mb+r)*1024 + hcol] = hb;
                        P.encout[((size_t)(mb+r)*Lseq + t)*Hd + hcol] = hb;
                    }
                    if (t == Lseq-1){
                        // stage h transposed for decoder t=0 (reads hT1)
                        sc_store_b32(P.hT1 + ((hcol*2+0)<<9) + (mb>>1), pack2(hvv[0], hvv[2]));
                        sc_store_b32(P.hT1 + ((hcol*2+1)<<9) + (mb>>1), pack2(hvv[1], hvv[3]));
                    }
                }
            }
        }
        if (t == Lseq-1) GSYNCL(); else XSYNC();
    }

    // ================= DECODER setup =================
    // dec weights -> LDS
    for (int i = tid; i < 64*64; i += 512){
        const int col = i >> 6, k8 = (i & 63)*8;
        const int g = (col & 3)*Hd + hc0 + (col >> 2);
        *reinterpret_cast<s16x8*>(&w1_lds[col*WSTRIDE + k8]) =
            *reinterpret_cast<const s16x8*>(P.dWih + (size_t)g*Hd + k8);
        *reinterpret_cast<s16x8*>(&w2_lds[col*WSTRIDE + k8]) =
            *reinterpret_cast<const s16x8*>(P.dWhh + (size_t)g*Hd + k8);
    }

    float bias_d[2];
#pragma unroll
    for (int nf = 0; nf < 2; ++nf)
        bias_d[nf] = bf2f(P.dbih[ng[nf]]) + bf2f(P.dbhh[ng[nf]]);

    const int b0 = grp*128 + rank*4;
    const int s_uni = b0 >> 9;
    const int p0 = b0 & (Hd-1);

    // enc_out slice -> registers: wave (rr, half) holds row b0+rr, l = half*25+i
    const int rr = wave & 3, half = wave >> 2;
    s16x8 ereg[25];
    {
        const bf16* eb = P.encout + (size_t)(b0 + rr)*Lseq*Hd + lane*8;
#pragma unroll
        for (int i = 0; i < 25; ++i)
            ereg[i] = *reinterpret_cast<const s16x8*>(eb + (size_t)(half*25 + i)*Hd);
    }

    // comb tile: wave covers rows bm0+wave*16, cols ccol
    const int ccol = hc0 + l15;   // 16 comb cols per WG (rank*16..+16)
    float bias_c, wxv_c[4];
    {
        bias_c = bf2f(P.cb[ccol]);
        const s16x4 t4 = *reinterpret_cast<const s16x4*>(P.cW + (size_t)ccol*(Hd+Din));
#pragma unroll
        for (int d = 0; d < 4; ++d) wxv_c[d] = bfbits2f(t4[d]);
    }
    __syncthreads();  // LDS fills complete

    for (int t = 0; t < Tlen; ++t){
        const int p = t & 1;
        const bf16* hprev = bufs[p] + Hd;

        // ---- D1: hr staging (coalesced from transposed hT) + pred(t-1) + attention ----
        {
            const bf16* hTr = (t & 1) ? P.hT0 : P.hT1;   // written prev step / by encoder
            const int q = tid >> 7;                      // 0..3 -> hr row
            const int i0 = (tid & 127) << 2;             // 0..508 step 4
            const s16x4 hv = sc_load_b64(hTr + (size_t)(((p0 + q)*2 + s_uni)<<9) + i0);
            *reinterpret_cast<s16x4*>(&hr_s[q][i0]) = hv;
        }
        __syncthreads();

        if (wave < 4){
            const int b = b0 + wave;
            float x0, x1, x2, x3;
            if (t == 0){
                const bf16* xp = P.input + ((size_t)b*Lseq + (Lseq-1))*Din;
                x0 = bf2f(xp[0]); x1 = bf2f(xp[1]); x2 = bf2f(xp[2]); x3 = bf2f(xp[3]);
            } else {
                float q0=0.f, q1=0.f, q2=0.f, q3=0.f;
                const bf16* hb = hprev + (size_t)b*1024;
                for (int k = lane; k < Hd; k += 64){
                    const float hv = bf2f(hb[k]);
                    q0 += hv*bf2f(P.oW[k]);
                    q1 += hv*bf2f(P.oW[Hd+k]);
                    q2 += hv*bf2f(P.oW[2*Hd+k]);
                    q3 += hv*bf2f(P.oW[3*Hd+k]);
                }
#pragma unroll
                for (int off = 32; off; off >>= 1){
                    q0 += __shfl_down(q0, off); q1 += __shfl_down(q1, off);
                    q2 += __shfl_down(q2, off); q3 += __shfl_down(q3, off);
                }
                x0 = __shfl(q0,0) + bf2f(P.ob[0]);
                x1 = __shfl(q1,0) + bf2f(P.ob[1]);
                x2 = __shfl(q2,0) + bf2f(P.ob[2]);
                x3 = __shfl(q3,0) + bf2f(P.ob[3]);
                if (lane == 0){
                    const size_t o = ((size_t)b*Tlen + (t-1))*Din;
                    if (f32out){
                        float* dp = (float*)P.dout + o;
                        dp[0]=x0; dp[1]=x1; dp[2]=x2; dp[3]=x3;
                    } else {
                        *reinterpret_cast<i32x2*>((bf16*)P.dout + o) = pack4(x0,x1,x2,x3);
                    }
                }
            }
            if (lane == 0)
                *reinterpret_cast<i32x2*>(P.xdec + (size_t)b*Din) = pack4(x0,x1,x2,x3);

            float logit = -3.0e38f;
            if (lane < Lseq){
                float a0 = bf2f(P.ab[lane]);
                {
                    const bf16* wx = P.aW + (size_t)lane*(Hd+Din);
                    a0 += x0*bf2f(wx[0]) + x1*bf2f(wx[1]) + x2*bf2f(wx[2]) + x3*bf2f(wx[3]);
                }
                float a1 = 0.f, a2 = 0.f, a3 = 0.f;
                const bf16* wr = P.attnWr + (size_t)lane*Hd;
                for (int j = 0; j < Hd; j += 16){
                    float t4[4] = {0.f,0.f,0.f,0.f};
#pragma unroll
                    for (int q = 0; q < 4; ++q){
                        const s16x4 hw = *reinterpret_cast<const s16x4*>(&hr_s[wave][j + q*4]);
                        const s16x4 wv = *reinterpret_cast<const s16x4*>(wr + j + q*4);
                        t4[q] = bfbits2f(hw[0])*bfbits2f(wv[0]) + bfbits2f(hw[1])*bfbits2f(wv[1])
                              + bfbits2f(hw[2])*bfbits2f(wv[2]) + bfbits2f(hw[3])*bfbits2f(wv[3]);
                    }
                    a0 += t4[0]; a1 += t4[1]; a2 += t4[2]; a3 += t4[3];
                }
                logit = (a0 + a1) + (a2 + a3);
            }
            float mx = logit;
#pragma unroll
            for (int off = 32; off; off >>= 1) mx = fmaxf(mx, __shfl_xor(mx, off));
            const float e = (lane < Lseq) ? __expf(logit - mx) : 0.0f;
            float se = e;
#pragma unroll
            for (int off = 32; off; off >>= 1) se += __shfl_xor(se, off);
            aw_s[wave][lane] = e / se;
        }
        __syncthreads();

        // context entirely from registers
        {
            float acc8[8] = {0.f,0.f,0.f,0.f,0.f,0.f,0.f,0.f};
#pragma unroll
            for (int i = 0; i < 25; ++i){
                const float w = aw_s[rr][half*25 + i];
#pragma unroll
                for (int q = 0; q < 8; ++q) acc8[q] += w * bfbits2f(ereg[i][q]);
            }
#pragma unroll
            for (int q = 0; q < 8; ++q) ctx_s[half][rr][q][lane] = acc8[q];
        }
        __syncthreads();

        if (wave < 4){
            const int b = b0 + wave;
            s16x8 ov;
#pragma unroll
            for (int q = 0; q < 8; ++q)
                ov[q] = f2bfbits(ctx_s[0][wave][q][lane] + ctx_s[1][wave][q][lane]);
            *reinterpret_cast<s16x8*>(P.attnap + (size_t)b*Hd + lane*8) = ov;
        }
        XSYNC();

        // ---- D2: comb GEMM (128 rows x 16 cols per WG) ----
        {
            f32x4 cacc = (f32x4)0.0f;
            const bf16* Ab = P.attnap + (size_t)(bm0 + wave*16 + l15)*Hd + quad*8;
#pragma unroll
            for (int kk = 0; kk < 16; ++kk){
                const s16x8 bfr = *reinterpret_cast<const s16x8*>(
                    P.combWr + (size_t)ccol*Hd + kk*32 + quad*8);
                const s16x8 afr2 = *reinterpret_cast<const s16x8*>(Ab + kk*32);
                cacc = __builtin_amdgcn_mfma_f32_16x16x32_bf16(afr2, bfr, cacc, 0, 0, 0);
            }
            bf16* outp = bufs[p];
#pragma unroll
            for (int r = 0; r < 4; ++r){
                const int m = bm0 + wave*16 + quad*4 + r;
                const s16x4 xt = *reinterpret_cast<const s16x4*>(P.xdec + (size_t)m*Din);
                float v = cacc[r] + bias_c
                        + bfbits2f(xt[0])*wxv_c[0] + bfbits2f(xt[1])*wxv_c[1]
                        + bfbits2f(xt[2])*wxv_c[2] + bfbits2f(xt[3])*wxv_c[3];
                v = fmaxf(v, 0.0f);
                outp[(size_t)m*1024 + ccol] = f2bf(v);
            }
        }
        XSYNC();

        // ---- D3: dec gates (K=1024: w1=W_ih, w2=W_hh from LDS) ----
        {
            const bf16* Ain = bufs[p];
            bf16* hout = bufs[p^1] + Hd;
            bf16* hTw = (t & 1) ? P.hT1 : P.hT0;   // next step reads this buffer
            f32x4 acc[2][2];
#pragma unroll
            for (int mf=0; mf<2; ++mf)
#pragma unroll
                for (int nf=0; nf<2; ++nf) acc[mf][nf] = (f32x4)0.0f;

            s16x8 afr[2], bfr[2];
#pragma unroll
            for (int sl = 0; sl < 16; ++sl){
#pragma unroll
                for (int mf = 0; mf < 2; ++mf)
                    afr[mf] = *reinterpret_cast<const s16x8*>(
                        Ain + (size_t)(arow0 + mf*16)*1024 + sl*32 + quad*8);
#pragma unroll
                for (int nf = 0; nf < 2; ++nf){
                    const int nl = wn*32 + nf*16 + l15;
                    bfr[nf] = *reinterpret_cast<const s16x8*>(
                        &w1_lds[nl*WSTRIDE + sl*32 + quad*8]);
                }
#pragma unroll
                for (int mf = 0; mf < 2; ++mf)
#pragma unroll
                    for (int nf = 0; nf < 2; ++nf)
                        acc[mf][nf] = __builtin_amdgcn_mfma_f32_16x16x32_bf16(
                            afr[mf], bfr[nf], acc[mf][nf], 0, 0, 0);
            }
#pragma unroll
            for (int sl = 0; sl < 16; ++sl){
#pragma unroll
                for (int mf = 0; mf < 2; ++mf)
                    afr[mf] = *reinterpret_cast<const s16x8*>(
                        Ain + (size_t)(arow0 + mf*16)*1024 + Hd + sl*32 + quad*8);
#pragma unroll
                for (int nf = 0; nf < 2; ++nf){
                    const int nl = wn*32 + nf*16 + l15;
                    bfr[nf] = *reinterpret_cast<const s16x8*>(
                        &w2_lds[nl*WSTRIDE + sl*32 + quad*8]);
                }
#pragma unroll
                for (int mf = 0; mf < 2; ++mf)
#pragma unroll
                    for (int nf = 0; nf < 2; ++nf)
                        acc[mf][nf] = __builtin_amdgcn_mfma_f32_16x16x32_bf16(
                            afr[mf], bfr[nf], acc[mf][nf], 0, 0, 0);
            }

#pragma unroll
            for (int mf = 0; mf < 2; ++mf){
                const int mb = bm0 + wm*32 + mf*16 + quad*4;
#pragma unroll
                for (int nf = 0; nf < 2; ++nf){
                    const int n_loc = wn*32 + nf*16 + l15;
                    float hvv[4];
#pragma unroll
                    for (int r = 0; r < 4; ++r){
                        float gv = acc[mf][nf][r] + bias_d[nf];
                        const float gi = __shfl(gv, lbase+0);
                        const float gf = __shfl(gv, lbase+1);
                        const float gg = __shfl(gv, lbase+2);
                        const float go = __shfl(gv, lbase+3);
                        const float cn = sigm(gf)*creg[mf][nf][r] + sigm(gi)*ftanh(gg);
                        creg[mf][nf][r] = cn;
                        hvv[r] = sigm(go)*ftanh(cn);
                    }
                    if ((lane & 3) == 0){
                        const int hcol = hc0 + (n_loc >> 2);
#pragma unroll
                        for (int r = 0; r < 4; ++r)
                            hout[(size_t)(mb+r)*1024 + hcol] = f2bf(hvv[r]);
                        // transposed staging for next step's h_r gather
                        sc_store_b32(hTw + ((hcol*2+0)<<9) + (mb>>1), pack2(hvv[0], hvv[2]));
                        sc_store_b32(hTw + ((hcol*2+1)<<9) + (mb>>1), pack2(hvv[1], hvv[3]));
                    }
                }
            }
        }
        GSYNCL();   // rank0 fence + counter round + L1 inv
    }

    // ---- final pred (t = T-1) ----
    if (wave < 4){
        const int b = b0 + wave;
        const bf16* hb = bufs[Tlen & 1] + Hd + (size_t)b*1024;
        float q0=0.f, q1=0.f, q2=0.f, q3=0.f;
        for (int k = lane; k < Hd; k += 64){
            const float hv = bf2f(hb[k]);
            q0 += hv*bf2f(P.oW[k]);
            q1 += hv*bf2f(P.oW[Hd+k]);
            q2 += hv*bf2f(P.oW[2*Hd+k]);
            q3 += hv*bf2f(P.oW[3*Hd+k]);
        }
#pragma unroll
        for (int off = 32; off; off >>= 1){
            q0 += __shfl_down(q0, off); q1 += __shfl_down(q1, off);
            q2 += __shfl_down(q2, off); q3 += __shfl_down(q3, off);
        }
        if (lane == 0){
            const size_t o = ((size_t)b*Tlen + (Tlen-1))*Din;
            const float r0 = q0 + bf2f(P.ob[0]), r1 = q1 + bf2f(P.ob[1]);
            const float r2 = q2 + bf2f(P.ob[2]), r3 = q3 + bf2f(P.ob[3]);
            if (f32out){
                float* dp = (float*)P.dout + o;
                dp[0]=r0; dp[1]=r1; dp[2]=r2; dp[3]=r3;
            } else {
                *reinterpret_cast<i32x2*>((bf16*)P.dout + o) = pack4(r0,r1,r2,r3);
            }
        }
    }
}

extern "C" void kernel_launch(void* const* d_in, const int* in_sizes, int n_in,
                              void* d_out, int out_size, void* d_ws, size_t ws_size,
                              hipStream_t stream)
{
    char* ws = (char*)d_ws;
    bf16*  Abuf0   = (bf16*)(ws + OFF_ABUF0);
    bf16*  Abuf1   = (bf16*)(ws + OFF_ABUF1);
    bf16*  hT0     = (bf16*)(ws + OFF_HT0);
    bf16*  hT1     = (bf16*)(ws + OFF_HT1);
    bf16*  attnap  = (bf16*)(ws + OFF_ATTNAP);
    bf16*  xdec    = (bf16*)(ws + OFF_XDEC);
    int*   flag    = (int*)(ws + OFF_FLAG);
    bf16*  combWr  = (bf16*)(ws + OFF_COMBWR);
    bf16*  attnWr  = (bf16*)(ws + OFF_ATTNWR);
    int*   flags   = (int*)(ws + OFF_FLAGS);
    bf16*  wc      = (bf16*)(ws + OFF_WCACHE);
    bf16*  enc_out = (bf16*)(ws + OFF_ENCOUT);

    // layout (ints): xcnt[g] at g*32 (128B lines), gcnt at 256 (own line),
    // grel[g] at 288+g*32, xccmap at 768..1023.
    hipMemsetAsync(flags, 0, 4096, stream);

    probe_kernel<<<1, 256, 0, stream>>>((const unsigned int*)d_in[3], flag);

    Ptrs15 srcs;
    srcs.p[0]=d_in[0];  srcs.p[1]=d_in[2];  srcs.p[2]=d_in[3];  srcs.p[3]=d_in[4];
    srcs.p[4]=d_in[5];  srcs.p[5]=d_in[6];  srcs.p[6]=d_in[7];  srcs.p[7]=d_in[8];
    srcs.p[8]=d_in[9];  srcs.p[9]=d_in[10]; srcs.p[10]=d_in[11];srcs.p[11]=d_in[12];
    srcs.p[12]=d_in[13];srcs.p[13]=d_in[14];srcs.p[14]=d_in[15];
    convert_kernel<<<1024, 256, 0, stream>>>(srcs, flag, wc);

    setup_kernel<<<2048, 256, 0, stream>>>(Abuf0, Abuf1, combWr, attnWr,
                                           wc+WC_CW, wc+WC_AW);

    MegaP P;
    P.input = wc+WC_INPUT; P.eWih = wc+WC_EWIH; P.eWhh = wc+WC_EWHH;
    P.ebih = wc+WC_EBIH;   P.ebhh = wc+WC_EBHH;
    P.aW = wc+WC_AW;  P.ab = wc+WC_AB;  P.cW = wc+WC_CW;  P.cb = wc+WC_CB;
    P.dWih = wc+WC_DWIH; P.dWhh = wc+WC_DWHH; P.dbih = wc+WC_DBIH; P.dbhh = wc+WC_DBHH;
    P.oW = wc+WC_OW;  P.ob = wc+WC_OB;
    P.combWr = combWr; P.attnWr = attnWr;
    P.A0 = Abuf0; P.A1 = Abuf1; P.encout = enc_out; P.attnap = attnap; P.xdec = xdec;
    P.hT0 = hT0; P.hT1 = hT1;
    P.xcnt = flags; P.gcnt = flags + 256; P.grel = flags + 288;
    P.xccmap = flags + 768;
    P.flag = flag; P.dout = d_out;

    mega_kernel<<<NWG, 512, 0, stream>>>(P);
}